// Round 3
// baseline (36481.204 us; speedup 1.0000x reference)
//
#include <hip/hip_runtime.h>

#define TT 2048
#define HD 64

// LDS arena byte map (2 rows/block):
//   h1 : [0, 1024)      parity p at (p<<9), row r at (r<<8); 16B blocks XOR-swizzled in each 256B row
//   h2 : [1088, 2112)   same layout, +64B skew so h1+h2 chunk reads cover all 32 banks
//   fcs: [2112, 2624)
#define H1_BASE 0
#define H2_BASE 1088
#define FCS_BASE 2112

// Gate pre-scales folded into weights/biases at load time:
//   sigmoid gates (i,f,o): t = -log2(e)*z   -> sigma(z) = rcp(1+exp2(t))
//   tanh gate (g):         t = -2*log2(e)*z -> tanh(z)  = 2*rcp(1+exp2(t)) - 1
#define SIC -1.4426950408889634f
#define SGC -2.8853900817779268f

#if __has_builtin(__builtin_amdgcn_exp2f)
#define EXP2F(x) __builtin_amdgcn_exp2f(x)
#else
#define EXP2F(x) __expf(0.69314718055994531f * (x))
#endif
#if __has_builtin(__builtin_amdgcn_rcpf)
#define RCPF(x) __builtin_amdgcn_rcpf(x)
#else
#define RCPF(x) (1.0f / (x))
#endif

// v_exp_f32 + v_add + v_rcp_f32: no IEEE div sequence.
__device__ __forceinline__ float rcp1p(float t) { return RCPF(1.0f + EXP2F(t)); }

// 16B-block swizzle within a 256B row: block index b in [0,16) -> byte offset
__device__ __forceinline__ int swz(int b) { return ((b ^ ((b >> 2) & 3)) << 4); }

// pure DPP quad_perm move. 0xB1 = quad_perm[1,0,3,2] (xor 1), 0x4E = quad_perm[2,3,0,1] (xor 2).
template<int CTRL>
__device__ __forceinline__ float dpp_get(float v) {
    return __int_as_float(__builtin_amdgcn_update_dpp(0, __float_as_int(v), CTRL, 0xF, 0xF, true));
}

__device__ __forceinline__ float4 scale4(float4 v, float s) {
    return make_float4(v.x * s, v.y * s, v.z * s, v.w * s);
}

#define DOT16(acc, W0, W1, W2, W3) \
    acc = __fmaf_rn(W0.x, hv0.x, acc); acc = __fmaf_rn(W0.y, hv0.y, acc); \
    acc = __fmaf_rn(W0.z, hv0.z, acc); acc = __fmaf_rn(W0.w, hv0.w, acc); \
    acc = __fmaf_rn(W1.x, hv1.x, acc); acc = __fmaf_rn(W1.y, hv1.y, acc); \
    acc = __fmaf_rn(W1.z, hv1.z, acc); acc = __fmaf_rn(W1.w, hv1.w, acc); \
    acc = __fmaf_rn(W2.x, hv2.x, acc); acc = __fmaf_rn(W2.y, hv2.y, acc); \
    acc = __fmaf_rn(W2.z, hv2.z, acc); acc = __fmaf_rn(W2.w, hv2.w, acc); \
    acc = __fmaf_rn(W3.x, hv3.x, acc); acc = __fmaf_rn(W3.y, hv3.y, acc); \
    acc = __fmaf_rn(W3.z, hv3.z, acc); acc = __fmaf_rn(W3.w, hv3.w, acc);

// seed accumulator from the first product (no per-step init movs)
#define DOT16I(acc, W0, W1, W2, W3) \
    acc = W0.x * hv0.x;                acc = __fmaf_rn(W0.y, hv0.y, acc); \
    acc = __fmaf_rn(W0.z, hv0.z, acc); acc = __fmaf_rn(W0.w, hv0.w, acc); \
    acc = __fmaf_rn(W1.x, hv1.x, acc); acc = __fmaf_rn(W1.y, hv1.y, acc); \
    acc = __fmaf_rn(W1.z, hv1.z, acc); acc = __fmaf_rn(W1.w, hv1.w, acc); \
    acc = __fmaf_rn(W2.x, hv2.x, acc); acc = __fmaf_rn(W2.y, hv2.y, acc); \
    acc = __fmaf_rn(W2.z, hv2.z, acc); acc = __fmaf_rn(W2.w, hv2.w, acc); \
    acc = __fmaf_rn(W3.x, hv3.x, acc); acc = __fmaf_rn(W3.y, hv3.y, acc); \
    acc = __fmaf_rn(W3.z, hv3.z, acc); acc = __fmaf_rn(W3.w, hv3.w, acc);

// P is a pointer-set prefix (pe/po); parity is baked into the pointers, so the
// whole read address is reg + compile-time immediate: zero per-step addressing.
#define ROWDOT(P, IMM, A0, A1, A2, A3) { \
    const float4 hv0 = *(const float4*)(P##0 + (IMM)); \
    const float4 hv1 = *(const float4*)(P##1 + (IMM)); \
    const float4 hv2 = *(const float4*)(P##2 + (IMM)); \
    const float4 hv3 = *(const float4*)(P##3 + (IMM)); \
    DOT16(A0, wA0, wA1, wA2, wA3); \
    DOT16(A1, wB0, wB1, wB2, wB3); \
    DOT16(A2, wC0, wC1, wC2, wC3); \
    DOT16(A3, wD0, wD1, wD2, wD3); }

// seeding variant: ALL FOUR accumulators start from their first product.
#define ROWDOTI(P, IMM, A0, A1, A2, A3) { \
    const float4 hv0 = *(const float4*)(P##0 + (IMM)); \
    const float4 hv1 = *(const float4*)(P##1 + (IMM)); \
    const float4 hv2 = *(const float4*)(P##2 + (IMM)); \
    const float4 hv3 = *(const float4*)(P##3 + (IMM)); \
    DOT16I(A0, wA0, wA1, wA2, wA3); \
    DOT16I(A1, wB0, wB1, wB2, wB3); \
    DOT16I(A2, wC0, wC1, wC2, wC3); \
    DOT16I(A3, wD0, wD1, wD2, wD3); }

// 2-row packed quad reduction: each lane ends with the full 4-chunk sum of
// row rr = rk&1 (lanes rk and rk^2 duplicate). Stage1 pre-swaps rows so the
// xor1 partner delivers MY row's other-chunk partial; stage2 is a plain xor2 add.
#define QRED2(e, r0, r1) \
    float e; { \
        float x_ = rr1 ? (r1) : (r0); \
        float y_ = rr1 ? (r0) : (r1); \
        x_ += dpp_get<0xB1>(y_); \
        e = x_ + dpp_get<0x4E>(x_); \
    }

// One pipelined timestep. P = pointer set (pe even / po odd), X = x-register
// set (xa even / xb odd), L0WOFF/L1WOFF = parity write offsets (compile-time),
// DO_L1 = literal gate for L1's act/store (false only at i=0), XNI = prefetch idx.
#define STEP(P, X, L0WOFF, L1WOFF, DO_L1, XNI)                                  \
{                                                                               \
    float a00, a01, a02, a03, a10, a11, a12, a13;                               \
    if (isL0) {                                                                 \
        const float xv0 = X##0, xv1 = X##1;                                     \
        {                                                                       \
            const int xi_ = (XNI) < TT ? (XNI) : (TT - 1);                      \
            X##0 = xp0[xi_]; X##1 = xp1[xi_];                                   \
        }                                                                       \
        a00 = __fmaf_rn(xv0, wxm0, bgm0); a01 = __fmaf_rn(xv0, wxm1, bgm1);     \
        a02 = __fmaf_rn(xv0, wxm2, bgm2); a03 = __fmaf_rn(xv0, wxm3, bgm3);     \
        a10 = __fmaf_rn(xv1, wxm0, bgm0); a11 = __fmaf_rn(xv1, wxm1, bgm1);     \
        a12 = __fmaf_rn(xv1, wxm2, bgm2); a13 = __fmaf_rn(xv1, wxm3, bgm3);     \
        ROWDOT(P, 0 * 256, a00, a01, a02, a03)                                  \
        ROWDOT(P, 1 * 256, a10, a11, a12, a13)                                  \
    } else {                                                                    \
        ROWDOTI(P, 0 * 256, a00, a01, a02, a03)                                 \
        ROWDOTI(P, 1 * 256, a10, a11, a12, a13)                                 \
    }                                                                           \
    QRED2(e0_, a00, a10)                                                        \
    QRED2(e1_, a01, a11)                                                        \
    QRED2(e2_, a02, a12)                                                        \
    QRED2(e3_, a03, a13)                                                        \
    if (isL0) {                                                                 \
        if (rk < 2) {                                                           \
            const float iv = rcp1p(e0_);                                        \
            const float fv = rcp1p(e1_);                                        \
            const float gv = __fmaf_rn(2.f, rcp1p(e2_), -1.f);                  \
            const float ov = rcp1p(e3_);                                        \
            cc = __fmaf_rn(fv, cc, iv * gv);                                    \
            const float th = __fmaf_rn(2.f, rcp1p(cc * SGC), -1.f);             \
            *(float*)(wraddr + (L0WOFF)) = ov * th;                             \
        }                                                                       \
    } else {                                                                    \
        e0_ += __shfl_xor(e0_, 4, 64);                                          \
        e1_ += __shfl_xor(e1_, 4, 64);                                          \
        e2_ += __shfl_xor(e2_, 4, 64);                                          \
        e3_ += __shfl_xor(e3_, 4, 64);                                          \
        if ((DO_L1) && ck < 2) {                                                \
            const float iv = rcp1p(e0_ + bgm0);                                 \
            const float fv = rcp1p(e1_ + bgm1);                                 \
            const float gv = __fmaf_rn(2.f, rcp1p(e2_ + bgm2), -1.f);           \
            const float ov = rcp1p(e3_ + bgm3);                                 \
            cc = __fmaf_rn(fv, cc, iv * gv);                                    \
            hlast = ov * __fmaf_rn(2.f, rcp1p(cc * SGC), -1.f);                 \
            *(float*)(wraddr + (L1WOFF)) = hlast;                               \
        }                                                                       \
    }                                                                           \
    __syncthreads();                                                            \
}

// Block = 768 threads, **2 batch rows per block, 2 blocks/CU** (grid 512).
//   waves 0-3  (tid 0..255):   layer0.  j=tid>>2 (unit), ck=tid&3  (16-wide K chunk of 64)
//   waves 4-11 (tid 256..767): layer1.  p=tid-256, j=p>>3, ck=p&7 (16-wide chunk of K=128=[h1|h2])
// Two co-resident blocks have INDEPENDENT barriers: one block's waves issue
// FMAs while the other drains its per-step s_barrier/lgkm wait.
// Pipeline: iter i does layer0 step i and layer1 step i-1; ONE barrier per iter.
__global__ __launch_bounds__(768, 6)
void lstm2_kernel(const float* __restrict__ x,
                  const float* __restrict__ Wih0,
                  const float* __restrict__ Whh0,
                  const float* __restrict__ bih0,
                  const float* __restrict__ bhh0,
                  const float* __restrict__ Wih1,
                  const float* __restrict__ Whh1,
                  const float* __restrict__ bih1,
                  const float* __restrict__ bhh1,
                  const float* __restrict__ fcW,
                  const float* __restrict__ fcb,
                  float* __restrict__ out)
{
    __shared__ __align__(16) float arena_f[656];
    char* const arena = (char*)arena_f;

    const int tid  = threadIdx.x;
    const int row0 = blockIdx.x * 2;

    const bool isL0 = (tid < 256);
    const int  p    = isL0 ? tid : (tid - 256);
    const int  j    = isL0 ? (p >> 2) : (p >> 3);
    const int  ck   = isL0 ? (p & 3)  : (p & 7);
    const int  ckk  = (ck < 4) ? ck : (ck - 4);
    const int  rk   = ck & 3;                      // quad lane id
    const bool rr1  = (rk & 1) != 0;               // this lane's row (0/1)

    // ---- weights: 16 explicit float4 registers, gate-prescaled at load ----
    const float* Wsrc;
    if (isL0)        Wsrc = Whh0;
    else if (ck < 4) Wsrc = Wih1;
    else             Wsrc = Whh1;
    const int kbase = 16 * ckk;
    const float4* W0p = (const float4*)(Wsrc + (0 * HD + j) * HD + kbase);
    const float4* W1p = (const float4*)(Wsrc + (1 * HD + j) * HD + kbase);
    const float4* W2p = (const float4*)(Wsrc + (2 * HD + j) * HD + kbase);
    const float4* W3p = (const float4*)(Wsrc + (3 * HD + j) * HD + kbase);
    const float4 wA0 = scale4(W0p[0], SIC), wA1 = scale4(W0p[1], SIC),
                 wA2 = scale4(W0p[2], SIC), wA3 = scale4(W0p[3], SIC);
    const float4 wB0 = scale4(W1p[0], SIC), wB1 = scale4(W1p[1], SIC),
                 wB2 = scale4(W1p[2], SIC), wB3 = scale4(W1p[3], SIC);
    const float4 wC0 = scale4(W2p[0], SGC), wC1 = scale4(W2p[1], SGC),
                 wC2 = scale4(W2p[2], SGC), wC3 = scale4(W2p[3], SGC);
    const float4 wD0 = scale4(W3p[0], SIC), wD1 = scale4(W3p[1], SIC),
                 wD2 = scale4(W3p[2], SIC), wD3 = scale4(W3p[3], SIC);

    // L0: masked (chunk 0 injects), pre-scaled bias + x-weight, used at acc init.
    // L1: unmasked pre-scaled bias, added post-reduction (after the xor-4 merge).
    float bgm0, bgm1, bgm2, bgm3, wxm0 = 0.f, wxm1 = 0.f, wxm2 = 0.f, wxm3 = 0.f;
    if (isL0) {
        const bool cz = (ck == 0);
        bgm0 = cz ? (bih0[0*HD+j] + bhh0[0*HD+j]) * SIC : 0.f;
        bgm1 = cz ? (bih0[1*HD+j] + bhh0[1*HD+j]) * SIC : 0.f;
        bgm2 = cz ? (bih0[2*HD+j] + bhh0[2*HD+j]) * SGC : 0.f;
        bgm3 = cz ? (bih0[3*HD+j] + bhh0[3*HD+j]) * SIC : 0.f;
        wxm0 = cz ? Wih0[0*HD+j] * SIC : 0.f;
        wxm1 = cz ? Wih0[1*HD+j] * SIC : 0.f;
        wxm2 = cz ? Wih0[2*HD+j] * SGC : 0.f;
        wxm3 = cz ? Wih0[3*HD+j] * SIC : 0.f;
    } else {
        bgm0 = (bih1[0*HD+j] + bhh1[0*HD+j]) * SIC;
        bgm1 = (bih1[1*HD+j] + bhh1[1*HD+j]) * SIC;
        bgm2 = (bih1[2*HD+j] + bhh1[2*HD+j]) * SGC;
        bgm3 = (bih1[3*HD+j] + bhh1[3*HD+j]) * SIC;
    }

    // per-thread LDS read constants; parity baked into TWO pointer sets so the
    // unrolled bodies use pure immediate offsets. Parity stride is 512B now.
    const int o0 = swz(4 * ckk + 0);
    const int o1 = swz(4 * ckk + 1);
    const int o2 = swz(4 * ckk + 2);
    const int o3 = swz(4 * ckk + 3);
    const int rdBase = (ck < 4) ? H1_BASE : H2_BASE;   // isL0 has ck<4
    const int rdPh   = (ck < 4) ? 1 : 0;               // h1 readers: (i+1)&1; h2: i&1

    const char* pe0 = arena + rdBase + (rdPh << 9) + o0;         // even-i bodies
    const char* pe1 = arena + rdBase + (rdPh << 9) + o1;
    const char* pe2 = arena + rdBase + (rdPh << 9) + o2;
    const char* pe3 = arena + rdBase + (rdPh << 9) + o3;
    const char* po0 = arena + rdBase + ((rdPh ^ 1) << 9) + o0;   // odd-i bodies
    const char* po1 = arena + rdBase + ((rdPh ^ 1) << 9) + o1;
    const char* po2 = arena + rdBase + ((rdPh ^ 1) << 9) + o2;
    const char* po3 = arena + rdBase + ((rdPh ^ 1) << 9) + o3;

    // writers are lanes rk<2; row = rk
    char* const wraddr = arena + (isL0 ? H1_BASE : H2_BASE)
                       + ((rk & 1) << 8) + swz(j >> 2) + ((j & 3) << 2);

    // zero both parities of h1 and h2 (swizzle is a bijection -> linear zero OK)
    for (int z = tid; z < 256; z += 768) {
        *(float*)(arena + H1_BASE + 4 * z) = 0.f;
        *(float*)(arena + H2_BASE + 4 * z) = 0.f;
    }

    const float* xp0 = x + (row0 + 0) * TT;
    const float* xp1 = x + (row0 + 1) * TT;
    float xa0 = 0.f, xa1 = 0.f;   // even-step x
    float xb0 = 0.f, xb1 = 0.f;   // odd-step x
    if (isL0) {
        xa0 = xp0[0]; xa1 = xp1[0];
        xb0 = xp0[1]; xb1 = xp1[1];
    }

    const float fcwj = fcW[j];
    float cc = 0.f, hlast = 0.f;

    __syncthreads();

    STEP(pe, xa, 0, 512, false, 2)      // i = 0: L0 only
    STEP(po, xb, 512, 0, true, 3)       // i = 1: first L1 step (step 0)
#pragma unroll 1
    for (int i = 2; i < TT; i += 2) {
        STEP(pe, xa, 0, 512, true, i + 2)
        STEP(po, xb, 512, 0, true, i + 3)
    }
    // tail i = 2048: layer1 step 2047 only (no L0, no h2 store needed)
    if (!isL0) {
        float a00, a01, a02, a03, a10, a11, a12, a13;
        ROWDOTI(pe, 0 * 256, a00, a01, a02, a03)
        ROWDOTI(pe, 1 * 256, a10, a11, a12, a13)
        QRED2(e0_, a00, a10)
        QRED2(e1_, a01, a11)
        QRED2(e2_, a02, a12)
        QRED2(e3_, a03, a13)
        e0_ += __shfl_xor(e0_, 4, 64);
        e1_ += __shfl_xor(e1_, 4, 64);
        e2_ += __shfl_xor(e2_, 4, 64);
        e3_ += __shfl_xor(e3_, 4, 64);
        if (ck < 2) {
            const float iv = rcp1p(e0_ + bgm0);
            const float fv = rcp1p(e1_ + bgm1);
            const float gv = __fmaf_rn(2.f, rcp1p(e2_ + bgm2), -1.f);
            const float ov = rcp1p(e3_ + bgm3);
            cc = __fmaf_rn(fv, cc, iv * gv);
            hlast = ov * __fmaf_rn(2.f, rcp1p(cc * SGC), -1.f);
        }
    }
    __syncthreads();

    // ---- FC: out[row] = sum_j h2[T-1][row][j] * fcW[j] + fcb ----
    if (!isL0 && ck < 2)
        *(float*)(arena + FCS_BASE + ((ck * HD + j) << 2)) = hlast * fcwj;
    __syncthreads();

    if (tid < 32) {
        const int r = tid >> 4, seg = tid & 15;
        const float4 v = ((const float4*)(arena + FCS_BASE))[r * 16 + seg];
        float s = (v.x + v.y) + (v.z + v.w);
        s += __shfl_xor(s, 1, 64);
        s += __shfl_xor(s, 2, 64);
        s += __shfl_xor(s, 4, 64);
        s += __shfl_xor(s, 8, 64);
        if (seg == 0) out[row0 + r] = s + fcb[0];
    }
}

extern "C" void kernel_launch(void* const* d_in, const int* in_sizes, int n_in,
                              void* d_out, int out_size, void* d_ws, size_t ws_size,
                              hipStream_t stream) {
    const float* x    = (const float*)d_in[0];
    const float* Wih0 = (const float*)d_in[1];
    const float* Whh0 = (const float*)d_in[2];
    const float* bih0 = (const float*)d_in[3];
    const float* bhh0 = (const float*)d_in[4];
    const float* Wih1 = (const float*)d_in[5];
    const float* Whh1 = (const float*)d_in[6];
    const float* bih1 = (const float*)d_in[7];
    const float* bhh1 = (const float*)d_in[8];
    const float* fcW  = (const float*)d_in[9];
    const float* fcb  = (const float*)d_in[10];
    float* out = (float*)d_out;

    lstm2_kernel<<<512, 768, 0, stream>>>(x, Wih0, Whh0, bih0, bhh0,
                                          Wih1, Whh1, bih1, bhh1,
                                          fcW, fcb, out);
}

// Round 5
// 3042.293 us; speedup vs baseline: 11.9914x; 11.9914x over previous
//
#include <hip/hip_runtime.h>

#define TT 2048
#define HD 64

// LDS arena byte map:
//   h1 : [0, 2048)      parity p, row r at (p*4+r)*256 B; 16B blocks XOR-swizzled
//   h2 : [2112, 4160)   same layout, +64B skew so h1+h2 chunk reads cover all 32 banks
//   fcs: [4160, 5184)
#define H1_BASE 0
#define H2_BASE 2112
#define FCS_BASE 4160

// Gate pre-scales folded into weights/biases at load time:
//   sigmoid gates (i,f,o): t = -log2(e)*z   -> sigma(z) = rcp(1+exp2(t))
//   tanh gate (g):         t = -2*log2(e)*z -> tanh(z)  = 2*rcp(1+exp2(t)) - 1
#define SIC -1.4426950408889634f
#define SGC -2.8853900817779268f

#if __has_builtin(__builtin_amdgcn_exp2f)
#define EXP2F(x) __builtin_amdgcn_exp2f(x)
#else
#define EXP2F(x) __expf(0.69314718055994531f * (x))
#endif
#if __has_builtin(__builtin_amdgcn_rcpf)
#define RCPF(x) __builtin_amdgcn_rcpf(x)
#else
#define RCPF(x) (1.0f / (x))
#endif

// v_exp_f32 + v_add + v_rcp_f32: no IEEE div sequence.
__device__ __forceinline__ float rcp1p(float t) { return RCPF(1.0f + EXP2F(t)); }

// 16B-block swizzle within a 256B row: block index b in [0,16) -> byte offset
__device__ __forceinline__ int swz(int b) { return ((b ^ ((b >> 2) & 3)) << 4); }

// pure DPP cross-lane move (stays OFF the LDS pipe).
// Semantics: receiver lane i gets in[(i - n) & 15] for row_ror:n (row_shr
// family delivers LOWER lanes' data upward; ror wraps).
// 0xB1 = quad_perm[1,0,3,2] (xor 1), 0x4E = quad_perm[2,3,0,1] (xor 2),
// 0x12C = row_ror:12 -> out[i] = in[(i-12)&15] = in[(i+4)&15]  (the +4 fetch).
template<int CTRL>
__device__ __forceinline__ float dpp_get(float v) {
    return __int_as_float(__builtin_amdgcn_update_dpp(0, __float_as_int(v), CTRL, 0xF, 0xF, true));
}

// Hot-loop barrier: order LDS ops only; let vmem/scalar prefetches ride across.
#define BARRIER() asm volatile("s_waitcnt lgkmcnt(0)\n\ts_barrier" ::: "memory")

__device__ __forceinline__ float4 scale4(float4 v, float s) {
    return make_float4(v.x * s, v.y * s, v.z * s, v.w * s);
}

#define DOT16(acc, W0, W1, W2, W3) \
    acc = __fmaf_rn(W0.x, hv0.x, acc); acc = __fmaf_rn(W0.y, hv0.y, acc); \
    acc = __fmaf_rn(W0.z, hv0.z, acc); acc = __fmaf_rn(W0.w, hv0.w, acc); \
    acc = __fmaf_rn(W1.x, hv1.x, acc); acc = __fmaf_rn(W1.y, hv1.y, acc); \
    acc = __fmaf_rn(W1.z, hv1.z, acc); acc = __fmaf_rn(W1.w, hv1.w, acc); \
    acc = __fmaf_rn(W2.x, hv2.x, acc); acc = __fmaf_rn(W2.y, hv2.y, acc); \
    acc = __fmaf_rn(W2.z, hv2.z, acc); acc = __fmaf_rn(W2.w, hv2.w, acc); \
    acc = __fmaf_rn(W3.x, hv3.x, acc); acc = __fmaf_rn(W3.y, hv3.y, acc); \
    acc = __fmaf_rn(W3.z, hv3.z, acc); acc = __fmaf_rn(W3.w, hv3.w, acc);

// seed accumulator from the first product (no per-step init movs)
#define DOT16I(acc, W0, W1, W2, W3) \
    acc = W0.x * hv0.x;                acc = __fmaf_rn(W0.y, hv0.y, acc); \
    acc = __fmaf_rn(W0.z, hv0.z, acc); acc = __fmaf_rn(W0.w, hv0.w, acc); \
    acc = __fmaf_rn(W1.x, hv1.x, acc); acc = __fmaf_rn(W1.y, hv1.y, acc); \
    acc = __fmaf_rn(W1.z, hv1.z, acc); acc = __fmaf_rn(W1.w, hv1.w, acc); \
    acc = __fmaf_rn(W2.x, hv2.x, acc); acc = __fmaf_rn(W2.y, hv2.y, acc); \
    acc = __fmaf_rn(W2.z, hv2.z, acc); acc = __fmaf_rn(W2.w, hv2.w, acc); \
    acc = __fmaf_rn(W3.x, hv3.x, acc); acc = __fmaf_rn(W3.y, hv3.y, acc); \
    acc = __fmaf_rn(W3.z, hv3.z, acc); acc = __fmaf_rn(W3.w, hv3.w, acc);

// P is a pointer-set prefix (pe/po); parity is baked into the pointers, so the
// whole read address is reg + compile-time immediate: zero per-step addressing.
#define ROWDOT(P, IMM, A0, A1, A2, A3) { \
    const float4 hv0 = *(const float4*)(P##0 + (IMM)); \
    const float4 hv1 = *(const float4*)(P##1 + (IMM)); \
    const float4 hv2 = *(const float4*)(P##2 + (IMM)); \
    const float4 hv3 = *(const float4*)(P##3 + (IMM)); \
    DOT16(A0, wA0, wA1, wA2, wA3); \
    DOT16(A1, wB0, wB1, wB2, wB3); \
    DOT16(A2, wC0, wC1, wC2, wC3); \
    DOT16(A3, wD0, wD1, wD2, wD3); }

// seeding variant: ALL FOUR accumulators start from their first product.
#define ROWDOTI(P, IMM, A0, A1, A2, A3) { \
    const float4 hv0 = *(const float4*)(P##0 + (IMM)); \
    const float4 hv1 = *(const float4*)(P##1 + (IMM)); \
    const float4 hv2 = *(const float4*)(P##2 + (IMM)); \
    const float4 hv3 = *(const float4*)(P##3 + (IMM)); \
    DOT16I(A0, wA0, wA1, wA2, wA3); \
    DOT16I(A1, wB0, wB1, wB2, wB3); \
    DOT16I(A2, wC0, wC1, wC2, wC3); \
    DOT16I(A3, wD0, wD1, wD2, wD3); }

// Packed row-select quad reduction: lane q (q = rk = lane&3 within the quad)
// ends with the full quad sum of row q's partials. 6 cndmask + 3 dpp-adds.
#define QRED(e, r0, r1, r2, r3) \
    float e; { \
        float x_ = q1 ? (r1) : (r0); float y_ = q1 ? (r0) : (r1); \
        x_ += dpp_get<0xB1>(y_); \
        float z_ = q1 ? (r3) : (r2); float w_ = q1 ? (r2) : (r3); \
        z_ += dpp_get<0xB1>(w_); \
        float u_ = q2 ? z_ : x_; float v_ = q2 ? x_ : z_; \
        e = u_ + dpp_get<0x4E>(v_); \
    }

// One pipelined timestep. P = pointer set (pe even / po odd), X = x-register
// set (xa even / xb odd), L0WOFF/L1WOFF = parity write offsets (compile-time),
// DO_L1 = literal gate for L1's act/store (false only at i=0), XNI = prefetch idx.
#define STEP(P, X, L0WOFF, L1WOFF, DO_L1, XNI)                                  \
{                                                                               \
    float a00, a01, a02, a03, a10, a11, a12, a13;                               \
    float a20, a21, a22, a23, a30, a31, a32, a33;                               \
    if (isL0) {                                                                 \
        const float xv0 = X##0, xv1 = X##1, xv2 = X##2, xv3 = X##3;             \
        {                                                                       \
            const int xi_ = (XNI) < TT ? (XNI) : (TT - 1);                      \
            X##0 = xp0[xi_]; X##1 = xp1[xi_];                                   \
            X##2 = xp2[xi_]; X##3 = xp3[xi_];                                   \
        }                                                                       \
        a00 = __fmaf_rn(xv0, wxm0, bgm0); a01 = __fmaf_rn(xv0, wxm1, bgm1);     \
        a02 = __fmaf_rn(xv0, wxm2, bgm2); a03 = __fmaf_rn(xv0, wxm3, bgm3);     \
        a10 = __fmaf_rn(xv1, wxm0, bgm0); a11 = __fmaf_rn(xv1, wxm1, bgm1);     \
        a12 = __fmaf_rn(xv1, wxm2, bgm2); a13 = __fmaf_rn(xv1, wxm3, bgm3);     \
        a20 = __fmaf_rn(xv2, wxm0, bgm0); a21 = __fmaf_rn(xv2, wxm1, bgm1);     \
        a22 = __fmaf_rn(xv2, wxm2, bgm2); a23 = __fmaf_rn(xv2, wxm3, bgm3);     \
        a30 = __fmaf_rn(xv3, wxm0, bgm0); a31 = __fmaf_rn(xv3, wxm1, bgm1);     \
        a32 = __fmaf_rn(xv3, wxm2, bgm2); a33 = __fmaf_rn(xv3, wxm3, bgm3);     \
        ROWDOT(P, 0 * 256, a00, a01, a02, a03)                                  \
        ROWDOT(P, 1 * 256, a10, a11, a12, a13)                                  \
        ROWDOT(P, 2 * 256, a20, a21, a22, a23)                                  \
        ROWDOT(P, 3 * 256, a30, a31, a32, a33)                                  \
    } else {                                                                    \
        ROWDOTI(P, 0 * 256, a00, a01, a02, a03)                                 \
        ROWDOTI(P, 1 * 256, a10, a11, a12, a13)                                 \
        ROWDOTI(P, 2 * 256, a20, a21, a22, a23)                                 \
        ROWDOTI(P, 3 * 256, a30, a31, a32, a33)                                 \
    }                                                                           \
    QRED(e0_, a00, a10, a20, a30)                                               \
    QRED(e1_, a01, a11, a21, a31)                                               \
    QRED(e2_, a02, a12, a22, a32)                                               \
    QRED(e3_, a03, a13, a23, a33)                                               \
    if (isL0) {                                                                 \
        const float iv = rcp1p(e0_);                                            \
        const float fv = rcp1p(e1_);                                            \
        const float gv = __fmaf_rn(2.f, rcp1p(e2_), -1.f);                      \
        const float ov = rcp1p(e3_);                                            \
        cc = __fmaf_rn(fv, cc, iv * gv);                                        \
        const float th = __fmaf_rn(2.f, rcp1p(cc * SGC), -1.f);                 \
        *(float*)(wraddr + (L0WOFF)) = ov * th;                                 \
    } else {                                                                    \
        /* cross-half (ck vs ck+4) combine on the VALU: row_ror:12 gives        \
           out[i]=in[(i+4)&15]. Lanes with ck>=4 receive junk (other j's quad)  \
           but never consume it (ck<4 gate below). */                           \
        e0_ += dpp_get<0x12C>(e0_);                                             \
        e1_ += dpp_get<0x12C>(e1_);                                             \
        e2_ += dpp_get<0x12C>(e2_);                                             \
        e3_ += dpp_get<0x12C>(e3_);                                             \
        if ((DO_L1) && ck < 4) {                                                \
            const float iv = rcp1p(e0_ + bgm0);                                 \
            const float fv = rcp1p(e1_ + bgm1);                                 \
            const float gv = __fmaf_rn(2.f, rcp1p(e2_ + bgm2), -1.f);           \
            const float ov = rcp1p(e3_ + bgm3);                                 \
            cc = __fmaf_rn(fv, cc, iv * gv);                                    \
            hlast = ov * __fmaf_rn(2.f, rcp1p(cc * SGC), -1.f);                 \
            *(float*)(wraddr + (L1WOFF)) = hlast;                               \
        }                                                                       \
    }                                                                           \
    BARRIER();                                                                  \
}

// Block = 768 threads, 4 batch rows per block, 1 block/CU (structure forced:
// the 49K-float weight set exactly fills 12 waves x 64 lanes x 64 floats of
// VGPR; a second co-resident barrier domain would need VGPR<=64 -> R3 disaster).
//   waves 0-3  (tid 0..255):   layer0.  j=tid>>2 (unit), ck=tid&3  (16-wide K chunk of 64)
//   waves 4-11 (tid 256..767): layer1.  p=tid-256, j=p>>3, ck=p&7 (16-wide chunk of K=128=[h1|h2])
// Pipeline: iter i does layer0 step i and layer1 step i-1; ONE barrier per iter.
__global__ __launch_bounds__(768, 3)
void lstm2_kernel(const float* __restrict__ x,
                  const float* __restrict__ Wih0,
                  const float* __restrict__ Whh0,
                  const float* __restrict__ bih0,
                  const float* __restrict__ bhh0,
                  const float* __restrict__ Wih1,
                  const float* __restrict__ Whh1,
                  const float* __restrict__ bih1,
                  const float* __restrict__ bhh1,
                  const float* __restrict__ fcW,
                  const float* __restrict__ fcb,
                  float* __restrict__ out)
{
    __shared__ __align__(16) float arena_f[1296];
    char* const arena = (char*)arena_f;

    const int tid  = threadIdx.x;
    const int row0 = blockIdx.x * 4;

    const bool isL0 = (tid < 256);
    const int  p    = isL0 ? tid : (tid - 256);
    const int  j    = isL0 ? (p >> 2) : (p >> 3);
    const int  ck   = isL0 ? (p & 3)  : (p & 7);
    const int  ckk  = (ck < 4) ? ck : (ck - 4);
    const int  rk   = ck & 3;                      // this lane's output row
    const bool q1   = (rk & 1) != 0;
    const bool q2   = (rk & 2) != 0;

    // ---- weights: 16 explicit float4 registers, gate-prescaled at load ----
    const float* Wsrc;
    if (isL0)        Wsrc = Whh0;
    else if (ck < 4) Wsrc = Wih1;
    else             Wsrc = Whh1;
    const int kbase = 16 * ckk;
    const float4* W0p = (const float4*)(Wsrc + (0 * HD + j) * HD + kbase);
    const float4* W1p = (const float4*)(Wsrc + (1 * HD + j) * HD + kbase);
    const float4* W2p = (const float4*)(Wsrc + (2 * HD + j) * HD + kbase);
    const float4* W3p = (const float4*)(Wsrc + (3 * HD + j) * HD + kbase);
    const float4 wA0 = scale4(W0p[0], SIC), wA1 = scale4(W0p[1], SIC),
                 wA2 = scale4(W0p[2], SIC), wA3 = scale4(W0p[3], SIC);
    const float4 wB0 = scale4(W1p[0], SIC), wB1 = scale4(W1p[1], SIC),
                 wB2 = scale4(W1p[2], SIC), wB3 = scale4(W1p[3], SIC);
    const float4 wC0 = scale4(W2p[0], SGC), wC1 = scale4(W2p[1], SGC),
                 wC2 = scale4(W2p[2], SGC), wC3 = scale4(W2p[3], SGC);
    const float4 wD0 = scale4(W3p[0], SIC), wD1 = scale4(W3p[1], SIC),
                 wD2 = scale4(W3p[2], SIC), wD3 = scale4(W3p[3], SIC);

    // L0: masked (chunk 0 injects), pre-scaled bias + x-weight, used at acc init.
    // L1: unmasked pre-scaled bias, added post-reduction (after the ror-4 merge).
    float bgm0, bgm1, bgm2, bgm3, wxm0 = 0.f, wxm1 = 0.f, wxm2 = 0.f, wxm3 = 0.f;
    if (isL0) {
        const bool cz = (ck == 0);
        bgm0 = cz ? (bih0[0*HD+j] + bhh0[0*HD+j]) * SIC : 0.f;
        bgm1 = cz ? (bih0[1*HD+j] + bhh0[1*HD+j]) * SIC : 0.f;
        bgm2 = cz ? (bih0[2*HD+j] + bhh0[2*HD+j]) * SGC : 0.f;
        bgm3 = cz ? (bih0[3*HD+j] + bhh0[3*HD+j]) * SIC : 0.f;
        wxm0 = cz ? Wih0[0*HD+j] * SIC : 0.f;
        wxm1 = cz ? Wih0[1*HD+j] * SIC : 0.f;
        wxm2 = cz ? Wih0[2*HD+j] * SGC : 0.f;
        wxm3 = cz ? Wih0[3*HD+j] * SIC : 0.f;
    } else {
        bgm0 = (bih1[0*HD+j] + bhh1[0*HD+j]) * SIC;
        bgm1 = (bih1[1*HD+j] + bhh1[1*HD+j]) * SIC;
        bgm2 = (bih1[2*HD+j] + bhh1[2*HD+j]) * SGC;
        bgm3 = (bih1[3*HD+j] + bhh1[3*HD+j]) * SIC;
    }

    // per-thread LDS read constants; parity baked into TWO pointer sets so the
    // unrolled bodies use pure immediate offsets.
    const int o0 = swz(4 * ckk + 0);
    const int o1 = swz(4 * ckk + 1);
    const int o2 = swz(4 * ckk + 2);
    const int o3 = swz(4 * ckk + 3);
    const int rdBase = (ck < 4) ? H1_BASE : H2_BASE;   // isL0 has ck<4
    const int rdPh   = (ck < 4) ? 1 : 0;               // h1 readers: (i+1)&1; h2: i&1

    const char* pe0 = arena + rdBase + (rdPh << 10) + o0;         // even-i bodies
    const char* pe1 = arena + rdBase + (rdPh << 10) + o1;
    const char* pe2 = arena + rdBase + (rdPh << 10) + o2;
    const char* pe3 = arena + rdBase + (rdPh << 10) + o3;
    const char* po0 = arena + rdBase + ((rdPh ^ 1) << 10) + o0;   // odd-i bodies
    const char* po1 = arena + rdBase + ((rdPh ^ 1) << 10) + o1;
    const char* po2 = arena + rdBase + ((rdPh ^ 1) << 10) + o2;
    const char* po3 = arena + rdBase + ((rdPh ^ 1) << 10) + o3;

    char* const wraddr = arena + (isL0 ? H1_BASE : H2_BASE)
                       + ((ck & 3) << 8) + swz(j >> 2) + ((j & 3) << 2);

    // zero both parities of h1 and h2 (swizzle is a bijection -> linear zero OK)
    for (int z = tid; z < 512; z += 768) {
        *(float*)(arena + H1_BASE + 4 * z) = 0.f;
        *(float*)(arena + H2_BASE + 4 * z) = 0.f;
    }

    const float* xp0 = x + (row0 + 0) * TT;
    const float* xp1 = x + (row0 + 1) * TT;
    const float* xp2 = x + (row0 + 2) * TT;
    const float* xp3 = x + (row0 + 3) * TT;
    float xa0 = 0.f, xa1 = 0.f, xa2 = 0.f, xa3 = 0.f;   // even-step x
    float xb0 = 0.f, xb1 = 0.f, xb2 = 0.f, xb3 = 0.f;   // odd-step x
    if (isL0) {
        xa0 = xp0[0]; xa1 = xp1[0]; xa2 = xp2[0]; xa3 = xp3[0];
        xb0 = xp0[1]; xb1 = xp1[1]; xb2 = xp2[1]; xb3 = xp3[1];
    }

    const float fcwj = fcW[j];
    float cc = 0.f, hlast = 0.f;

    __syncthreads();

    STEP(pe, xa, 0, 1024, false, 2)      // i = 0: L0 only
    STEP(po, xb, 1024, 0, true, 3)       // i = 1: first L1 step (step 0)
#pragma unroll 1
    for (int i = 2; i < TT; i += 2) {
        STEP(pe, xa, 0, 1024, true, i + 2)
        STEP(po, xb, 1024, 0, true, i + 3)
    }
    // tail i = 2048: layer1 step 2047 only (no L0, no h2 store needed)
    if (!isL0) {
        float a00, a01, a02, a03, a10, a11, a12, a13;
        float a20, a21, a22, a23, a30, a31, a32, a33;
        ROWDOTI(pe, 0 * 256, a00, a01, a02, a03)
        ROWDOTI(pe, 1 * 256, a10, a11, a12, a13)
        ROWDOTI(pe, 2 * 256, a20, a21, a22, a23)
        ROWDOTI(pe, 3 * 256, a30, a31, a32, a33)
        QRED(e0_, a00, a10, a20, a30)
        QRED(e1_, a01, a11, a21, a31)
        QRED(e2_, a02, a12, a22, a32)
        QRED(e3_, a03, a13, a23, a33)
        e0_ += dpp_get<0x12C>(e0_);
        e1_ += dpp_get<0x12C>(e1_);
        e2_ += dpp_get<0x12C>(e2_);
        e3_ += dpp_get<0x12C>(e3_);
        if (ck < 4) {
            const float iv = rcp1p(e0_ + bgm0);
            const float fv = rcp1p(e1_ + bgm1);
            const float gv = __fmaf_rn(2.f, rcp1p(e2_ + bgm2), -1.f);
            const float ov = rcp1p(e3_ + bgm3);
            cc = __fmaf_rn(fv, cc, iv * gv);
            hlast = ov * __fmaf_rn(2.f, rcp1p(cc * SGC), -1.f);
        }
    }
    __syncthreads();

    // ---- FC: out[row] = sum_j h2[T-1][row][j] * fcW[j] + fcb ----
    if (!isL0 && ck < 4)
        *(float*)(arena + FCS_BASE + ((ck * HD + j) << 2)) = hlast * fcwj;
    __syncthreads();

    if (tid < 64) {
        const int r = tid >> 4, seg = tid & 15;
        const float4 v = ((const float4*)(arena + FCS_BASE))[r * 16 + seg];
        float s = (v.x + v.y) + (v.z + v.w);
        s += __shfl_xor(s, 1, 64);
        s += __shfl_xor(s, 2, 64);
        s += __shfl_xor(s, 4, 64);
        s += __shfl_xor(s, 8, 64);
        if (seg == 0) out[row0 + r] = s + fcb[0];
    }
}

extern "C" void kernel_launch(void* const* d_in, const int* in_sizes, int n_in,
                              void* d_out, int out_size, void* d_ws, size_t ws_size,
                              hipStream_t stream) {
    const float* x    = (const float*)d_in[0];
    const float* Wih0 = (const float*)d_in[1];
    const float* Whh0 = (const float*)d_in[2];
    const float* bih0 = (const float*)d_in[3];
    const float* bhh0 = (const float*)d_in[4];
    const float* Wih1 = (const float*)d_in[5];
    const float* Whh1 = (const float*)d_in[6];
    const float* bih1 = (const float*)d_in[7];
    const float* bhh1 = (const float*)d_in[8];
    const float* fcW  = (const float*)d_in[9];
    const float* fcb  = (const float*)d_in[10];
    float* out = (float*)d_out;

    lstm2_kernel<<<256, 768, 0, stream>>>(x, Wih0, Whh0, bih0, bhh0,
                                          Wih1, Whh1, bih1, bhh1,
                                          fcW, fcb, out);
}

// Round 6
// 3010.004 us; speedup vs baseline: 12.1200x; 1.0107x over previous
//
#include <hip/hip_runtime.h>

#define TT 2048
#define HD 64

// LDS arena byte map:
//   h1 : [0, 2048)      parity p, row r at (p*4+r)*256 B; 16B blocks XOR-swizzled
//   h2 : [2112, 4160)   same layout, +64B skew so h1+h2 chunk reads cover all 32 banks
//   fcs: [4160, 5184)
#define H1_BASE 0
#define H2_BASE 2112
#define FCS_BASE 4160

// Gate pre-scales folded into weights/biases at load time:
//   sigmoid gates (i,f,o): t = -log2(e)*z   -> sigma(z) = rcp(1+exp2(t))
//   tanh gate (g):         t = -2*log2(e)*z -> tanh(z)  = 2*rcp(1+exp2(t)) - 1
#define SIC -1.4426950408889634f
#define SGC -2.8853900817779268f

#if __has_builtin(__builtin_amdgcn_exp2f)
#define EXP2F(x) __builtin_amdgcn_exp2f(x)
#else
#define EXP2F(x) __expf(0.69314718055994531f * (x))
#endif
#if __has_builtin(__builtin_amdgcn_rcpf)
#define RCPF(x) __builtin_amdgcn_rcpf(x)
#else
#define RCPF(x) (1.0f / (x))
#endif

// v_exp_f32 + v_add + v_rcp_f32: no IEEE div sequence.
__device__ __forceinline__ float rcp1p(float t) { return RCPF(1.0f + EXP2F(t)); }

// 16B-block swizzle within a 256B row: block index b in [0,16) -> byte offset
__device__ __forceinline__ int swz(int b) { return ((b ^ ((b >> 2) & 3)) << 4); }

// pure DPP cross-lane move (stays OFF the LDS pipe).
// Receiver lane i gets in[(i-n)&15] for row_ror:n.
// 0xB1 = quad_perm[1,0,3,2] (xor 1), 0x4E = quad_perm[2,3,0,1] (xor 2),
// 0x12C = row_ror:12 -> out[i] = in[(i+4)&15]  (the +4 fetch, verified R5).
template<int CTRL>
__device__ __forceinline__ float dpp_get(float v) {
    return __int_as_float(__builtin_amdgcn_update_dpp(0, __float_as_int(v), CTRL, 0xF, 0xF, true));
}

// Hot-loop barrier: order LDS ops only; let vmem/scalar prefetches ride across.
#define BARRIER() asm volatile("s_waitcnt lgkmcnt(0)\n\ts_barrier" ::: "memory")

__device__ __forceinline__ float4 scale4(float4 v, float s) {
    return make_float4(v.x * s, v.y * s, v.z * s, v.w * s);
}

// ---- packed fp32 (VOP3P v_pk_fma_f32) dot kernel ----
typedef float v2f __attribute__((ext_vector_type(2)));
static __device__ __forceinline__ v2f lo2(float4 v) { v2f r; r[0] = v.x; r[1] = v.y; return r; }
static __device__ __forceinline__ v2f hi2(float4 v) { v2f r; r[0] = v.z; r[1] = v.w; return r; }
#if __has_builtin(__builtin_elementwise_fma)
#define FMA2(a, b, c) __builtin_elementwise_fma((a), (b), (c))
#else
#define FMA2(a, b, c) ((a) * (b) + (c))
#endif

// 16-K dot for one gate as 8 packed FMAs; first op seeds (no init mov).
#define PDOT16I(acc, W0, W1, W2, W3) \
    acc = lo2(W0) * lo2(hv0);           acc = FMA2(hi2(W0), hi2(hv0), acc); \
    acc = FMA2(lo2(W1), lo2(hv1), acc); acc = FMA2(hi2(W1), hi2(hv1), acc); \
    acc = FMA2(lo2(W2), lo2(hv2), acc); acc = FMA2(hi2(W2), hi2(hv2), acc); \
    acc = FMA2(lo2(W3), lo2(hv3), acc); acc = FMA2(hi2(W3), hi2(hv3), acc);

// P is a pointer-set prefix (pe/po); parity baked into pointers -> pure
// reg+immediate LDS addressing. Loads one h-row, accumulates 4 gates packed.
#define ROWDOTP(P, IMM, A0, A1, A2, A3) { \
    const float4 hv0 = *(const float4*)(P##0 + (IMM)); \
    const float4 hv1 = *(const float4*)(P##1 + (IMM)); \
    const float4 hv2 = *(const float4*)(P##2 + (IMM)); \
    const float4 hv3 = *(const float4*)(P##3 + (IMM)); \
    PDOT16I(A0, wA0, wA1, wA2, wA3); \
    PDOT16I(A1, wB0, wB1, wB2, wB3); \
    PDOT16I(A2, wC0, wC1, wC2, wC3); \
    PDOT16I(A3, wD0, wD1, wD2, wD3); }

// Packed row-select quad reduction: lane q (q = rk) ends with the full quad
// sum of row q's partials. 6 cndmask + 3 dpp-adds.
#define QRED(e, r0, r1, r2, r3) \
    float e; { \
        float x_ = q1 ? (r1) : (r0); float y_ = q1 ? (r0) : (r1); \
        x_ += dpp_get<0xB1>(y_); \
        float z_ = q1 ? (r3) : (r2); float w_ = q1 ? (r2) : (r3); \
        z_ += dpp_get<0xB1>(w_); \
        float u_ = q2 ? z_ : x_; float v_ = q2 ? x_ : z_; \
        e = u_ + dpp_get<0x4E>(v_); \
    }

// One pipelined timestep. P = pointer set (pe even / po odd), X = x register
// (xa even / xb odd; scalar — each L0 lane streams only ITS row rk's x),
// L0WOFF/L1WOFF = parity write offsets, DO_L1 gates L1 act/store, XNI = prefetch.
// L0's bias + x*Wih inject happens POST-QRED (once per lane) so no masking and
// no 16-FMA init block; both layers seed accumulators inside ROWDOTP.
#define STEP(P, X, L0WOFF, L1WOFF, DO_L1, XNI)                                  \
{                                                                               \
    float xv = 0.f;                                                             \
    if (isL0) {                                                                 \
        xv = X;                                                                 \
        const int xi_ = (XNI) < TT ? (XNI) : (TT - 1);                          \
        X = xps[xi_];                                                           \
    }                                                                           \
    v2f a00, a01, a02, a03, a10, a11, a12, a13;                                 \
    v2f a20, a21, a22, a23, a30, a31, a32, a33;                                 \
    ROWDOTP(P, 0 * 256, a00, a01, a02, a03)                                     \
    ROWDOTP(P, 1 * 256, a10, a11, a12, a13)                                     \
    ROWDOTP(P, 2 * 256, a20, a21, a22, a23)                                     \
    ROWDOTP(P, 3 * 256, a30, a31, a32, a33)                                     \
    const float s00 = a00[0] + a00[1], s01 = a01[0] + a01[1];                   \
    const float s02 = a02[0] + a02[1], s03 = a03[0] + a03[1];                   \
    const float s10 = a10[0] + a10[1], s11 = a11[0] + a11[1];                   \
    const float s12 = a12[0] + a12[1], s13 = a13[0] + a13[1];                   \
    const float s20 = a20[0] + a20[1], s21 = a21[0] + a21[1];                   \
    const float s22 = a22[0] + a22[1], s23 = a23[0] + a23[1];                   \
    const float s30 = a30[0] + a30[1], s31 = a31[0] + a31[1];                   \
    const float s32 = a32[0] + a32[1], s33 = a33[0] + a33[1];                   \
    QRED(e0_, s00, s10, s20, s30)                                               \
    QRED(e1_, s01, s11, s21, s31)                                               \
    QRED(e2_, s02, s12, s22, s32)                                               \
    QRED(e3_, s03, s13, s23, s33)                                               \
    if (isL0) {                                                                 \
        const float iv = rcp1p(__fmaf_rn(xv, wxm0, bgm0) + e0_);                \
        const float fv = rcp1p(__fmaf_rn(xv, wxm1, bgm1) + e1_);                \
        const float gv = __fmaf_rn(2.f, rcp1p(__fmaf_rn(xv, wxm2, bgm2) + e2_), -1.f); \
        const float ov = rcp1p(__fmaf_rn(xv, wxm3, bgm3) + e3_);                \
        cc = __fmaf_rn(fv, cc, iv * gv);                                        \
        const float th = __fmaf_rn(2.f, rcp1p(cc * SGC), -1.f);                 \
        *(float*)(wraddr + (L0WOFF)) = ov * th;                                 \
    } else {                                                                    \
        /* cross-half (ck vs ck+4) combine: row_ror:12 -> in[(i+4)&15].         \
           Lanes ck>=4 receive junk but never consume (ck<4 gate). */           \
        e0_ += dpp_get<0x12C>(e0_);                                             \
        e1_ += dpp_get<0x12C>(e1_);                                             \
        e2_ += dpp_get<0x12C>(e2_);                                             \
        e3_ += dpp_get<0x12C>(e3_);                                             \
        if ((DO_L1) && ck < 4) {                                                \
            const float iv = rcp1p(e0_ + bgm0);                                 \
            const float fv = rcp1p(e1_ + bgm1);                                 \
            const float gv = __fmaf_rn(2.f, rcp1p(e2_ + bgm2), -1.f);           \
            const float ov = rcp1p(e3_ + bgm3);                                 \
            cc = __fmaf_rn(fv, cc, iv * gv);                                    \
            hlast = ov * __fmaf_rn(2.f, rcp1p(cc * SGC), -1.f);                 \
            *(float*)(wraddr + (L1WOFF)) = hlast;                               \
        }                                                                       \
    }                                                                           \
    BARRIER();                                                                  \
}

// Block = 768 threads, 4 batch rows per block, 1 block/CU (structure forced:
// the 49K-float weight set exactly fills 12 waves x 64 lanes x 64 floats of
// VGPR; a second co-resident barrier domain would need VGPR<=64 -> R3 disaster).
//   waves 0-3  (tid 0..255):   layer0.  j=tid>>2 (unit), ck=tid&3  (16-wide K chunk of 64)
//   waves 4-11 (tid 256..767): layer1.  p=tid-256, j=p>>3, ck=p&7 (16-wide chunk of K=128=[h1|h2])
// Pipeline: iter i does layer0 step i and layer1 step i-1; ONE barrier per iter.
__global__ __launch_bounds__(768, 3)
void lstm2_kernel(const float* __restrict__ x,
                  const float* __restrict__ Wih0,
                  const float* __restrict__ Whh0,
                  const float* __restrict__ bih0,
                  const float* __restrict__ bhh0,
                  const float* __restrict__ Wih1,
                  const float* __restrict__ Whh1,
                  const float* __restrict__ bih1,
                  const float* __restrict__ bhh1,
                  const float* __restrict__ fcW,
                  const float* __restrict__ fcb,
                  float* __restrict__ out)
{
    __shared__ __align__(16) float arena_f[1296];
    char* const arena = (char*)arena_f;

    const int tid  = threadIdx.x;
    const int row0 = blockIdx.x * 4;

    const bool isL0 = (tid < 256);
    const int  p    = isL0 ? tid : (tid - 256);
    const int  j    = isL0 ? (p >> 2) : (p >> 3);
    const int  ck   = isL0 ? (p & 3)  : (p & 7);
    const int  ckk  = (ck < 4) ? ck : (ck - 4);
    const int  rk   = ck & 3;                      // this lane's output row
    const bool q1   = (rk & 1) != 0;
    const bool q2   = (rk & 2) != 0;

    // ---- weights: 16 explicit float4 registers, gate-prescaled at load ----
    const float* Wsrc;
    if (isL0)        Wsrc = Whh0;
    else if (ck < 4) Wsrc = Wih1;
    else             Wsrc = Whh1;
    const int kbase = 16 * ckk;
    const float4* W0p = (const float4*)(Wsrc + (0 * HD + j) * HD + kbase);
    const float4* W1p = (const float4*)(Wsrc + (1 * HD + j) * HD + kbase);
    const float4* W2p = (const float4*)(Wsrc + (2 * HD + j) * HD + kbase);
    const float4* W3p = (const float4*)(Wsrc + (3 * HD + j) * HD + kbase);
    const float4 wA0 = scale4(W0p[0], SIC), wA1 = scale4(W0p[1], SIC),
                 wA2 = scale4(W0p[2], SIC), wA3 = scale4(W0p[3], SIC);
    const float4 wB0 = scale4(W1p[0], SIC), wB1 = scale4(W1p[1], SIC),
                 wB2 = scale4(W1p[2], SIC), wB3 = scale4(W1p[3], SIC);
    const float4 wC0 = scale4(W2p[0], SGC), wC1 = scale4(W2p[1], SGC),
                 wC2 = scale4(W2p[2], SGC), wC3 = scale4(W2p[3], SGC);
    const float4 wD0 = scale4(W3p[0], SIC), wD1 = scale4(W3p[1], SIC),
                 wD2 = scale4(W3p[2], SIC), wD3 = scale4(W3p[3], SIC);

    // Biases / x-weights, pre-scaled, UNMASKED (added exactly once per lane,
    // post-reduction, on both layers).
    float bgm0, bgm1, bgm2, bgm3, wxm0 = 0.f, wxm1 = 0.f, wxm2 = 0.f, wxm3 = 0.f;
    if (isL0) {
        bgm0 = (bih0[0*HD+j] + bhh0[0*HD+j]) * SIC;
        bgm1 = (bih0[1*HD+j] + bhh0[1*HD+j]) * SIC;
        bgm2 = (bih0[2*HD+j] + bhh0[2*HD+j]) * SGC;
        bgm3 = (bih0[3*HD+j] + bhh0[3*HD+j]) * SIC;
        wxm0 = Wih0[0*HD+j] * SIC;
        wxm1 = Wih0[1*HD+j] * SIC;
        wxm2 = Wih0[2*HD+j] * SGC;
        wxm3 = Wih0[3*HD+j] * SIC;
    } else {
        bgm0 = (bih1[0*HD+j] + bhh1[0*HD+j]) * SIC;
        bgm1 = (bih1[1*HD+j] + bhh1[1*HD+j]) * SIC;
        bgm2 = (bih1[2*HD+j] + bhh1[2*HD+j]) * SGC;
        bgm3 = (bih1[3*HD+j] + bhh1[3*HD+j]) * SIC;
    }

    // per-thread LDS read constants; parity baked into TWO pointer sets so the
    // unrolled bodies use pure immediate offsets.
    const int o0 = swz(4 * ckk + 0);
    const int o1 = swz(4 * ckk + 1);
    const int o2 = swz(4 * ckk + 2);
    const int o3 = swz(4 * ckk + 3);
    const int rdBase = (ck < 4) ? H1_BASE : H2_BASE;   // isL0 has ck<4
    const int rdPh   = (ck < 4) ? 1 : 0;               // h1 readers: (i+1)&1; h2: i&1

    const char* pe0 = arena + rdBase + (rdPh << 10) + o0;         // even-i bodies
    const char* pe1 = arena + rdBase + (rdPh << 10) + o1;
    const char* pe2 = arena + rdBase + (rdPh << 10) + o2;
    const char* pe3 = arena + rdBase + (rdPh << 10) + o3;
    const char* po0 = arena + rdBase + ((rdPh ^ 1) << 10) + o0;   // odd-i bodies
    const char* po1 = arena + rdBase + ((rdPh ^ 1) << 10) + o1;
    const char* po2 = arena + rdBase + ((rdPh ^ 1) << 10) + o2;
    const char* po3 = arena + rdBase + ((rdPh ^ 1) << 10) + o3;

    char* const wraddr = arena + (isL0 ? H1_BASE : H2_BASE)
                       + ((ck & 3) << 8) + swz(j >> 2) + ((j & 3) << 2);

    // zero both parities of h1 and h2 (swizzle is a bijection -> linear zero OK)
    for (int z = tid; z < 512; z += 768) {
        *(float*)(arena + H1_BASE + 4 * z) = 0.f;
        *(float*)(arena + H2_BASE + 4 * z) = 0.f;
    }

    // Each L0 lane streams only ITS row's x (lane rk -> batch row row0+rk).
    const float* xps = x + (row0 + rk) * TT;
    float xa = 0.f, xb = 0.f;
    if (isL0) { xa = xps[0]; xb = xps[1]; }

    const float fcwj = fcW[j];
    float cc = 0.f, hlast = 0.f;

    __syncthreads();

    STEP(pe, xa, 0, 1024, false, 2)      // i = 0: L0 only
    STEP(po, xb, 1024, 0, true, 3)       // i = 1: first L1 step (step 0)
#pragma unroll 1
    for (int i = 2; i < TT; i += 2) {
        STEP(pe, xa, 0, 1024, true, i + 2)
        STEP(po, xb, 1024, 0, true, i + 3)
    }
    // tail i = 2048: layer1 step 2047 only (no L0, no h2 store needed)
    if (!isL0) {
        v2f a00, a01, a02, a03, a10, a11, a12, a13;
        v2f a20, a21, a22, a23, a30, a31, a32, a33;
        ROWDOTP(pe, 0 * 256, a00, a01, a02, a03)
        ROWDOTP(pe, 1 * 256, a10, a11, a12, a13)
        ROWDOTP(pe, 2 * 256, a20, a21, a22, a23)
        ROWDOTP(pe, 3 * 256, a30, a31, a32, a33)
        const float s00 = a00[0] + a00[1], s01 = a01[0] + a01[1];
        const float s02 = a02[0] + a02[1], s03 = a03[0] + a03[1];
        const float s10 = a10[0] + a10[1], s11 = a11[0] + a11[1];
        const float s12 = a12[0] + a12[1], s13 = a13[0] + a13[1];
        const float s20 = a20[0] + a20[1], s21 = a21[0] + a21[1];
        const float s22 = a22[0] + a22[1], s23 = a23[0] + a23[1];
        const float s30 = a30[0] + a30[1], s31 = a31[0] + a31[1];
        const float s32 = a32[0] + a32[1], s33 = a33[0] + a33[1];
        QRED(e0_, s00, s10, s20, s30)
        QRED(e1_, s01, s11, s21, s31)
        QRED(e2_, s02, s12, s22, s32)
        QRED(e3_, s03, s13, s23, s33)
        e0_ += dpp_get<0x12C>(e0_);
        e1_ += dpp_get<0x12C>(e1_);
        e2_ += dpp_get<0x12C>(e2_);
        e3_ += dpp_get<0x12C>(e3_);
        if (ck < 4) {
            const float iv = rcp1p(e0_ + bgm0);
            const float fv = rcp1p(e1_ + bgm1);
            const float gv = __fmaf_rn(2.f, rcp1p(e2_ + bgm2), -1.f);
            const float ov = rcp1p(e3_ + bgm3);
            cc = __fmaf_rn(fv, cc, iv * gv);
            hlast = ov * __fmaf_rn(2.f, rcp1p(cc * SGC), -1.f);
        }
    }
    __syncthreads();

    // ---- FC: out[row] = sum_j h2[T-1][row][j] * fcW[j] + fcb ----
    if (!isL0 && ck < 4)
        *(float*)(arena + FCS_BASE + ((ck * HD + j) << 2)) = hlast * fcwj;
    __syncthreads();

    if (tid < 64) {
        const int r = tid >> 4, seg = tid & 15;
        const float4 v = ((const float4*)(arena + FCS_BASE))[r * 16 + seg];
        float s = (v.x + v.y) + (v.z + v.w);
        s += __shfl_xor(s, 1, 64);
        s += __shfl_xor(s, 2, 64);
        s += __shfl_xor(s, 4, 64);
        s += __shfl_xor(s, 8, 64);
        if (seg == 0) out[row0 + r] = s + fcb[0];
    }
}

extern "C" void kernel_launch(void* const* d_in, const int* in_sizes, int n_in,
                              void* d_out, int out_size, void* d_ws, size_t ws_size,
                              hipStream_t stream) {
    const float* x    = (const float*)d_in[0];
    const float* Wih0 = (const float*)d_in[1];
    const float* Whh0 = (const float*)d_in[2];
    const float* bih0 = (const float*)d_in[3];
    const float* bhh0 = (const float*)d_in[4];
    const float* Wih1 = (const float*)d_in[5];
    const float* Whh1 = (const float*)d_in[6];
    const float* bih1 = (const float*)d_in[7];
    const float* bhh1 = (const float*)d_in[8];
    const float* fcW  = (const float*)d_in[9];
    const float* fcb  = (const float*)d_in[10];
    float* out = (float*)d_out;

    lstm2_kernel<<<256, 768, 0, stream>>>(x, Wih0, Whh0, bih0, bhh0,
                                          Wih1, Whh1, bih1, bhh1,
                                          fcW, fcb, out);
}

// Round 7
// 2912.835 us; speedup vs baseline: 12.5243x; 1.0334x over previous
//
#include <hip/hip_runtime.h>

#define TT 2048
#define HD 64

// LDS arena byte map:
//   h1 : [0, 2048)      parity p, row r at (p*4+r)*256 B; 16B blocks XOR-swizzled
//   h2 : [2112, 4160)   same layout, +64B skew so h1+h2 chunk reads cover all 32 banks
//   fcs: [4160, 5184)
#define H1_BASE 0
#define H2_BASE 2112
#define FCS_BASE 4160

// Gate pre-scales folded into weights/biases at load time:
//   sigmoid gates (i,f,o): t = -log2(e)*z   -> sigma(z) = rcp(1+exp2(t))
//   tanh gate (g):         t = -2*log2(e)*z -> tanh(z)  = 2*rcp(1+exp2(t)) - 1
#define SIC -1.4426950408889634f
#define SGC -2.8853900817779268f

#if __has_builtin(__builtin_amdgcn_exp2f)
#define EXP2F(x) __builtin_amdgcn_exp2f(x)
#else
#define EXP2F(x) __expf(0.69314718055994531f * (x))
#endif
#if __has_builtin(__builtin_amdgcn_rcpf)
#define RCPF(x) __builtin_amdgcn_rcpf(x)
#else
#define RCPF(x) (1.0f / (x))
#endif

// v_exp_f32 + v_add + v_rcp_f32: no IEEE div sequence.
__device__ __forceinline__ float rcp1p(float t) { return RCPF(1.0f + EXP2F(t)); }

// 16B-block swizzle within a 256B row: block index b in [0,16) -> byte offset
__device__ __forceinline__ int swz(int b) { return ((b ^ ((b >> 2) & 3)) << 4); }

// pure DPP cross-lane move (stays OFF the LDS pipe).
// Receiver lane i gets in[(i-n)&15] for row_ror:n.
// 0xB1 = quad_perm[1,0,3,2] (xor 1), 0x4E = quad_perm[2,3,0,1] (xor 2),
// 0x12C = row_ror:12 -> out[i] = in[(i+4)&15]  (the +4 fetch, verified R5).
template<int CTRL>
__device__ __forceinline__ float dpp_get(float v) {
    return __int_as_float(__builtin_amdgcn_update_dpp(0, __float_as_int(v), CTRL, 0xF, 0xF, true));
}

// Hot-loop barrier: order LDS ops only; let vmem/scalar prefetches ride across.
#define BARRIER() asm volatile("s_waitcnt lgkmcnt(0)\n\ts_barrier" ::: "memory")

__device__ __forceinline__ float4 scale4(float4 v, float s) {
    return make_float4(v.x * s, v.y * s, v.z * s, v.w * s);
}

// 16-K scalar dot for one gate; first op seeds the accumulator (no init mov).
// Packed FP32 was tested (R6) and is issue-rate-neutral on gfx950 (157.3 TF
// spec == scalar issue rate) — scalar is simpler and frees the pair constraint.
#define DOT16I(acc, W0, W1, W2, W3) \
    acc = W0.x * hv0.x;                acc = __fmaf_rn(W0.y, hv0.y, acc); \
    acc = __fmaf_rn(W0.z, hv0.z, acc); acc = __fmaf_rn(W0.w, hv0.w, acc); \
    acc = __fmaf_rn(W1.x, hv1.x, acc); acc = __fmaf_rn(W1.y, hv1.y, acc); \
    acc = __fmaf_rn(W1.z, hv1.z, acc); acc = __fmaf_rn(W1.w, hv1.w, acc); \
    acc = __fmaf_rn(W2.x, hv2.x, acc); acc = __fmaf_rn(W2.y, hv2.y, acc); \
    acc = __fmaf_rn(W2.z, hv2.z, acc); acc = __fmaf_rn(W2.w, hv2.w, acc); \
    acc = __fmaf_rn(W3.x, hv3.x, acc); acc = __fmaf_rn(W3.y, hv3.y, acc); \
    acc = __fmaf_rn(W3.w, hv3.w, acc); acc = __fmaf_rn(W3.z, hv3.z, acc);

// P is a pointer-set prefix (pe/po); parity baked into pointers -> pure
// reg+immediate LDS addressing. Loads one h-row chunk, accumulates 4 gates.
#define ROWDOTI(P, IMM, A0, A1, A2, A3) { \
    const float4 hv0 = *(const float4*)(P##0 + (IMM)); \
    const float4 hv1 = *(const float4*)(P##1 + (IMM)); \
    const float4 hv2 = *(const float4*)(P##2 + (IMM)); \
    const float4 hv3 = *(const float4*)(P##3 + (IMM)); \
    DOT16I(A0, wA0, wA1, wA2, wA3); \
    DOT16I(A1, wB0, wB1, wB2, wB3); \
    DOT16I(A2, wC0, wC1, wC2, wC3); \
    DOT16I(A3, wD0, wD1, wD2, wD3); }

// Packed row-select quad reduction: lane q (q = rk) ends with the full quad
// sum of row q's partials. 6 cndmask + 3 dpp-adds.
#define QRED(e, r0, r1, r2, r3) \
    float e; { \
        float x_ = q1 ? (r1) : (r0); float y_ = q1 ? (r0) : (r1); \
        x_ += dpp_get<0xB1>(y_); \
        float z_ = q1 ? (r3) : (r2); float w_ = q1 ? (r2) : (r3); \
        z_ += dpp_get<0xB1>(w_); \
        float u_ = q2 ? z_ : x_; float v_ = q2 ? x_ : z_; \
        e = u_ + dpp_get<0x4E>(v_); \
    }

// One pipelined timestep. P = pointer set (pe even / po odd), X = x register
// (xa even / xb odd; scalar — each L0 lane streams only ITS row rk's x),
// L0WOFF/L1WOFF = parity write offsets, DO_L1 gates L1 act/store, XNI = prefetch.
// L0's bias + x*Wih inject happens POST-QRED (once per lane) so no masking and
// no init-FMA block; both layers seed accumulators inside ROWDOTI.
#define STEP(P, X, L0WOFF, L1WOFF, DO_L1, XNI)                                  \
{                                                                               \
    float xv = 0.f;                                                             \
    if (isL0) {                                                                 \
        xv = X;                                                                 \
        const int xi_ = (XNI) < TT ? (XNI) : (TT - 1);                          \
        X = xps[xi_];                                                           \
    }                                                                           \
    float a00, a01, a02, a03, a10, a11, a12, a13;                               \
    float a20, a21, a22, a23, a30, a31, a32, a33;                               \
    ROWDOTI(P, 0 * 256, a00, a01, a02, a03)                                     \
    ROWDOTI(P, 1 * 256, a10, a11, a12, a13)                                     \
    ROWDOTI(P, 2 * 256, a20, a21, a22, a23)                                     \
    ROWDOTI(P, 3 * 256, a30, a31, a32, a33)                                     \
    QRED(e0_, a00, a10, a20, a30)                                               \
    QRED(e1_, a01, a11, a21, a31)                                               \
    QRED(e2_, a02, a12, a22, a32)                                               \
    QRED(e3_, a03, a13, a23, a33)                                               \
    if (isL0) {                                                                 \
        const float iv = rcp1p(__fmaf_rn(xv, wxm0, bgm0) + e0_);                \
        const float fv = rcp1p(__fmaf_rn(xv, wxm1, bgm1) + e1_);                \
        const float gv = __fmaf_rn(2.f, rcp1p(__fmaf_rn(xv, wxm2, bgm2) + e2_), -1.f); \
        const float ov = rcp1p(__fmaf_rn(xv, wxm3, bgm3) + e3_);                \
        cc = __fmaf_rn(fv, cc, iv * gv);                                        \
        const float th = __fmaf_rn(2.f, rcp1p(cc * SGC), -1.f);                 \
        *(float*)(wraddr + (L0WOFF)) = ov * th;                                 \
    } else {                                                                    \
        /* cross-half (ck vs ck+4) combine: row_ror:12 -> in[(i+4)&15].         \
           Lanes ck>=4 receive junk but never consume (ck<4 gate). */           \
        e0_ += dpp_get<0x12C>(e0_);                                             \
        e1_ += dpp_get<0x12C>(e1_);                                             \
        e2_ += dpp_get<0x12C>(e2_);                                             \
        e3_ += dpp_get<0x12C>(e3_);                                             \
        if ((DO_L1) && ck < 4) {                                                \
            const float iv = rcp1p(e0_ + bgm0);                                 \
            const float fv = rcp1p(e1_ + bgm1);                                 \
            const float gv = __fmaf_rn(2.f, rcp1p(e2_ + bgm2), -1.f);           \
            const float ov = rcp1p(e3_ + bgm3);                                 \
            cc = __fmaf_rn(fv, cc, iv * gv);                                    \
            hlast = ov * __fmaf_rn(2.f, rcp1p(cc * SGC), -1.f);                 \
            *(float*)(wraddr + (L1WOFF)) = hlast;                               \
        }                                                                       \
    }                                                                           \
    BARRIER();                                                                  \
}

// Block = 768 threads, 4 batch rows per block, 1 block/CU (structure forced:
// the 49K-float weight set exactly fills 12 waves x 64 lanes x 64 floats of
// VGPR; a second co-resident barrier domain would need VGPR<=64 -> R3 disaster).
//   waves 0-3  (tid 0..255):   layer0.  j=tid>>2 (unit), ck=tid&3  (16-wide K chunk of 64)
//   waves 4-11 (tid 256..767): layer1.  p=tid-256, j=p>>3, ck=p&7 (16-wide chunk of K=128=[h1|h2])
// Pipeline: iter i does layer0 step i and layer1 step i-1; ONE barrier per iter.
__global__ __launch_bounds__(768, 3)
void lstm2_kernel(const float* __restrict__ x,
                  const float* __restrict__ Wih0,
                  const float* __restrict__ Whh0,
                  const float* __restrict__ bih0,
                  const float* __restrict__ bhh0,
                  const float* __restrict__ Wih1,
                  const float* __restrict__ Whh1,
                  const float* __restrict__ bih1,
                  const float* __restrict__ bhh1,
                  const float* __restrict__ fcW,
                  const float* __restrict__ fcb,
                  float* __restrict__ out)
{
    __shared__ __align__(16) float arena_f[1296];
    char* const arena = (char*)arena_f;

    const int tid  = threadIdx.x;
    const int row0 = blockIdx.x * 4;

    const bool isL0 = (tid < 256);
    const int  p    = isL0 ? tid : (tid - 256);
    const int  j    = isL0 ? (p >> 2) : (p >> 3);
    const int  ck   = isL0 ? (p & 3)  : (p & 7);
    const int  ckk  = (ck < 4) ? ck : (ck - 4);
    const int  rk   = ck & 3;                      // this lane's output row
    const bool q1   = (rk & 1) != 0;
    const bool q2   = (rk & 2) != 0;

    // ---- weights: 16 explicit float4 registers, gate-prescaled at load ----
    const float* Wsrc;
    if (isL0)        Wsrc = Whh0;
    else if (ck < 4) Wsrc = Wih1;
    else             Wsrc = Whh1;
    const int kbase = 16 * ckk;
    const float4* W0p = (const float4*)(Wsrc + (0 * HD + j) * HD + kbase);
    const float4* W1p = (const float4*)(Wsrc + (1 * HD + j) * HD + kbase);
    const float4* W2p = (const float4*)(Wsrc + (2 * HD + j) * HD + kbase);
    const float4* W3p = (const float4*)(Wsrc + (3 * HD + j) * HD + kbase);
    const float4 wA0 = scale4(W0p[0], SIC), wA1 = scale4(W0p[1], SIC),
                 wA2 = scale4(W0p[2], SIC), wA3 = scale4(W0p[3], SIC);
    const float4 wB0 = scale4(W1p[0], SIC), wB1 = scale4(W1p[1], SIC),
                 wB2 = scale4(W1p[2], SIC), wB3 = scale4(W1p[3], SIC);
    const float4 wC0 = scale4(W2p[0], SGC), wC1 = scale4(W2p[1], SGC),
                 wC2 = scale4(W2p[2], SGC), wC3 = scale4(W2p[3], SGC);
    const float4 wD0 = scale4(W3p[0], SIC), wD1 = scale4(W3p[1], SIC),
                 wD2 = scale4(W3p[2], SIC), wD3 = scale4(W3p[3], SIC);

    // Biases / x-weights, pre-scaled, UNMASKED (added exactly once per lane,
    // post-reduction, on both layers).
    float bgm0, bgm1, bgm2, bgm3, wxm0 = 0.f, wxm1 = 0.f, wxm2 = 0.f, wxm3 = 0.f;
    if (isL0) {
        bgm0 = (bih0[0*HD+j] + bhh0[0*HD+j]) * SIC;
        bgm1 = (bih0[1*HD+j] + bhh0[1*HD+j]) * SIC;
        bgm2 = (bih0[2*HD+j] + bhh0[2*HD+j]) * SGC;
        bgm3 = (bih0[3*HD+j] + bhh0[3*HD+j]) * SIC;
        wxm0 = Wih0[0*HD+j] * SIC;
        wxm1 = Wih0[1*HD+j] * SIC;
        wxm2 = Wih0[2*HD+j] * SGC;
        wxm3 = Wih0[3*HD+j] * SIC;
    } else {
        bgm0 = (bih1[0*HD+j] + bhh1[0*HD+j]) * SIC;
        bgm1 = (bih1[1*HD+j] + bhh1[1*HD+j]) * SIC;
        bgm2 = (bih1[2*HD+j] + bhh1[2*HD+j]) * SGC;
        bgm3 = (bih1[3*HD+j] + bhh1[3*HD+j]) * SIC;
    }

    // per-thread LDS read constants; parity baked into TWO pointer sets so the
    // unrolled bodies use pure immediate offsets.
    const int o0 = swz(4 * ckk + 0);
    const int o1 = swz(4 * ckk + 1);
    const int o2 = swz(4 * ckk + 2);
    const int o3 = swz(4 * ckk + 3);
    const int rdBase = (ck < 4) ? H1_BASE : H2_BASE;   // isL0 has ck<4
    const int rdPh   = (ck < 4) ? 1 : 0;               // h1 readers: (i+1)&1; h2: i&1

    const char* pe0 = arena + rdBase + (rdPh << 10) + o0;         // even-i bodies
    const char* pe1 = arena + rdBase + (rdPh << 10) + o1;
    const char* pe2 = arena + rdBase + (rdPh << 10) + o2;
    const char* pe3 = arena + rdBase + (rdPh << 10) + o3;
    const char* po0 = arena + rdBase + ((rdPh ^ 1) << 10) + o0;   // odd-i bodies
    const char* po1 = arena + rdBase + ((rdPh ^ 1) << 10) + o1;
    const char* po2 = arena + rdBase + ((rdPh ^ 1) << 10) + o2;
    const char* po3 = arena + rdBase + ((rdPh ^ 1) << 10) + o3;

    char* const wraddr = arena + (isL0 ? H1_BASE : H2_BASE)
                       + ((ck & 3) << 8) + swz(j >> 2) + ((j & 3) << 2);

    // zero both parities of h1 and h2 (swizzle is a bijection -> linear zero OK)
    for (int z = tid; z < 512; z += 768) {
        *(float*)(arena + H1_BASE + 4 * z) = 0.f;
        *(float*)(arena + H2_BASE + 4 * z) = 0.f;
    }

    // Each L0 lane streams only ITS row's x (lane rk -> batch row row0+rk).
    const float* xps = x + (row0 + rk) * TT;
    float xa = 0.f, xb = 0.f;
    if (isL0) { xa = xps[0]; xb = xps[1]; }

    const float fcwj = fcW[j];
    float cc = 0.f, hlast = 0.f;

    __syncthreads();

    STEP(pe, xa, 0, 1024, false, 2)      // i = 0: L0 only
    STEP(po, xb, 1024, 0, true, 3)       // i = 1: first L1 step (step 0)
#pragma unroll 1
    for (int i = 2; i < TT; i += 2) {
        STEP(pe, xa, 0, 1024, true, i + 2)
        STEP(po, xb, 1024, 0, true, i + 3)
    }
    // tail i = 2048: layer1 step 2047 only (no L0, no h2 store needed)
    if (!isL0) {
        float a00, a01, a02, a03, a10, a11, a12, a13;
        float a20, a21, a22, a23, a30, a31, a32, a33;
        ROWDOTI(pe, 0 * 256, a00, a01, a02, a03)
        ROWDOTI(pe, 1 * 256, a10, a11, a12, a13)
        ROWDOTI(pe, 2 * 256, a20, a21, a22, a23)
        ROWDOTI(pe, 3 * 256, a30, a31, a32, a33)
        QRED(e0_, a00, a10, a20, a30)
        QRED(e1_, a01, a11, a21, a31)
        QRED(e2_, a02, a12, a22, a32)
        QRED(e3_, a03, a13, a23, a33)
        e0_ += dpp_get<0x12C>(e0_);
        e1_ += dpp_get<0x12C>(e1_);
        e2_ += dpp_get<0x12C>(e2_);
        e3_ += dpp_get<0x12C>(e3_);
        if (ck < 4) {
            const float iv = rcp1p(e0_ + bgm0);
            const float fv = rcp1p(e1_ + bgm1);
            const float gv = __fmaf_rn(2.f, rcp1p(e2_ + bgm2), -1.f);
            const float ov = rcp1p(e3_ + bgm3);
            cc = __fmaf_rn(fv, cc, iv * gv);
            hlast = ov * __fmaf_rn(2.f, rcp1p(cc * SGC), -1.f);
        }
    }
    __syncthreads();

    // ---- FC: out[row] = sum_j h2[T-1][row][j] * fcW[j] + fcb ----
    if (!isL0 && ck < 4)
        *(float*)(arena + FCS_BASE + ((ck * HD + j) << 2)) = hlast * fcwj;
    __syncthreads();

    if (tid < 64) {
        const int r = tid >> 4, seg = tid & 15;
        const float4 v = ((const float4*)(arena + FCS_BASE))[r * 16 + seg];
        float s = (v.x + v.y) + (v.z + v.w);
        s += __shfl_xor(s, 1, 64);
        s += __shfl_xor(s, 2, 64);
        s += __shfl_xor(s, 4, 64);
        s += __shfl_xor(s, 8, 64);
        if (seg == 0) out[row0 + r] = s + fcb[0];
    }
}

extern "C" void kernel_launch(void* const* d_in, const int* in_sizes, int n_in,
                              void* d_out, int out_size, void* d_ws, size_t ws_size,
                              hipStream_t stream) {
    const float* x    = (const float*)d_in[0];
    const float* Wih0 = (const float*)d_in[1];
    const float* Whh0 = (const float*)d_in[2];
    const float* bih0 = (const float*)d_in[3];
    const float* bhh0 = (const float*)d_in[4];
    const float* Wih1 = (const float*)d_in[5];
    const float* Whh1 = (const float*)d_in[6];
    const float* bih1 = (const float*)d_in[7];
    const float* bhh1 = (const float*)d_in[8];
    const float* fcW  = (const float*)d_in[9];
    const float* fcb  = (const float*)d_in[10];
    float* out = (float*)d_out;

    lstm2_kernel<<<256, 768, 0, stream>>>(x, Wih0, Whh0, bih0, bhh0,
                                          Wih1, Whh1, bih1, bhh1,
                                          fcW, fcb, out);
}

// Round 8
// 2795.599 us; speedup vs baseline: 13.0495x; 1.0419x over previous
//
#include <hip/hip_runtime.h>

#define TT 2048
#define HD 64

// LDS arena, h stored as FP16 (c stays f32 in registers; only h is quantized):
//   h1 : [0, 1280)      parity p at p*640, row r at r*160 (row stride 160B
//                        spreads row bases across banks 0/8/16/24), unit j at j*2
//   h2 : [1344, 2624)   same layout, +64B skew
//   fcs: [2624, 3648)   f32 FC staging
#define H1_BASE 0
#define H2_BASE 1344
#define FCS_BASE 2624
#define PSTR 640
#define RSTR 160

// Gate pre-scales folded into (fp16) weights/biases at load time:
//   sigmoid gates (i,f,o): t = -log2(e)*z   -> sigma(z) = rcp(1+exp2(t))
//   tanh gate (g):         t = -2*log2(e)*z -> tanh(z)  = 2*rcp(1+exp2(t)) - 1
#define SIC -1.4426950408889634f
#define SGC -2.8853900817779268f

#if __has_builtin(__builtin_amdgcn_exp2f)
#define EXP2F(x) __builtin_amdgcn_exp2f(x)
#else
#define EXP2F(x) __expf(0.69314718055994531f * (x))
#endif
#if __has_builtin(__builtin_amdgcn_rcpf)
#define RCPF(x) __builtin_amdgcn_rcpf(x)
#else
#define RCPF(x) (1.0f / (x))
#endif

__device__ __forceinline__ float rcp1p(float t) { return RCPF(1.0f + EXP2F(t)); }

typedef _Float16 v2h __attribute__((ext_vector_type(2)));

// v_dot2_f32_f16: 2 fp16 products + f32 accumulate in ONE VALU instr.
#if __has_builtin(__builtin_amdgcn_fdot2)
#define FDOT2(a, b, c) __builtin_amdgcn_fdot2((a), (b), (c), false)
#else
#define FDOT2(a, b, c) __fmaf_rn((float)(a)[1], (float)(b)[1], __fmaf_rn((float)(a)[0], (float)(b)[0], (c)))
#endif

static __device__ __forceinline__ v2h bch(float f) { return __builtin_bit_cast(v2h, f); }
static __device__ __forceinline__ v2h packw(float a, float b, float s) {
    v2h r; r[0] = (_Float16)(a * s); r[1] = (_Float16)(b * s); return r;
}

// pure DPP cross-lane move (stays OFF the LDS pipe).
// Receiver lane i gets in[(i-n)&15] for row_ror:n.
// 0xB1 = quad_perm xor1, 0x4E = quad_perm xor2,
// 0x12C = row_ror:12 -> out[i] = in[(i+4)&15]  (the +4 fetch, verified R5).
template<int CTRL>
__device__ __forceinline__ float dpp_get(float v) {
    return __int_as_float(__builtin_amdgcn_update_dpp(0, __float_as_int(v), CTRL, 0xF, 0xF, true));
}

// Hot-loop barrier: order LDS ops only; let vmem/scalar prefetches ride across.
#define BARRIER() asm volatile("s_waitcnt lgkmcnt(0)\n\ts_barrier" ::: "memory")

// 16-K dot for one gate: 8 fdot2, first seeds from c=0 (inline const, no mov).
#define GDOT8I(acc, W) \
    acc = FDOT2(W##0, h0_, 0.0f); \
    acc = FDOT2(W##1, h1_, acc);  \
    acc = FDOT2(W##2, h2_, acc);  \
    acc = FDOT2(W##3, h3_, acc);  \
    acc = FDOT2(W##4, h4_, acc);  \
    acc = FDOT2(W##5, h5_, acc);  \
    acc = FDOT2(W##6, h6_, acc);  \
    acc = FDOT2(W##7, h7_, acc);

// One h-row (16 fp16 = 32B) in TWO ds_read_b128; 4 gates = 32 fdot2.
// P = pointer-set prefix (pe/po), parity baked in -> reg+imm addressing.
#define ROWDOTH(P, ROFF, A0, A1, A2, A3) { \
    const float4 f0_ = *(const float4*)(P##0 + (ROFF)); \
    const float4 f1_ = *(const float4*)(P##1 + (ROFF)); \
    const v2h h0_ = bch(f0_.x), h1_ = bch(f0_.y), h2_ = bch(f0_.z), h3_ = bch(f0_.w); \
    const v2h h4_ = bch(f1_.x), h5_ = bch(f1_.y), h6_ = bch(f1_.z), h7_ = bch(f1_.w); \
    GDOT8I(A0, wA) \
    GDOT8I(A1, wB) \
    GDOT8I(A2, wC) \
    GDOT8I(A3, wD) }

// Packed row-select quad reduction: lane q (q = rk) ends with the full quad
// sum of row q's partials. 6 cndmask + 3 dpp-adds.
#define QRED(e, r0, r1, r2, r3) \
    float e; { \
        float x_ = q1 ? (r1) : (r0); float y_ = q1 ? (r0) : (r1); \
        x_ += dpp_get<0xB1>(y_); \
        float z_ = q1 ? (r3) : (r2); float w_ = q1 ? (r2) : (r3); \
        z_ += dpp_get<0xB1>(w_); \
        float u_ = q2 ? z_ : x_; float v_ = q2 ? x_ : z_; \
        e = u_ + dpp_get<0x4E>(v_); \
    }

// One pipelined timestep. P = pointer set (pe even / po odd), X = x register
// (xa even / xb odd; each L0 lane streams only ITS row rk's x stream),
// L0WOFF/L1WOFF = parity write byte offsets (0 / PSTR), DO_L1 gates L1,
// XNI = x prefetch index. Bias + x*Wih inject POST-QRED (once per lane).
#define STEP(P, X, L0WOFF, L1WOFF, DO_L1, XNI)                                  \
{                                                                               \
    float xv = 0.f;                                                             \
    if (isL0) {                                                                 \
        xv = X;                                                                 \
        const int xi_ = (XNI) < TT ? (XNI) : (TT - 1);                          \
        X = xps[xi_];                                                           \
    }                                                                           \
    float a00, a01, a02, a03, a10, a11, a12, a13;                               \
    float a20, a21, a22, a23, a30, a31, a32, a33;                               \
    ROWDOTH(P, 0 * RSTR, a00, a01, a02, a03)                                    \
    ROWDOTH(P, 1 * RSTR, a10, a11, a12, a13)                                    \
    ROWDOTH(P, 2 * RSTR, a20, a21, a22, a23)                                    \
    ROWDOTH(P, 3 * RSTR, a30, a31, a32, a33)                                    \
    QRED(e0_, a00, a10, a20, a30)                                               \
    QRED(e1_, a01, a11, a21, a31)                                               \
    QRED(e2_, a02, a12, a22, a32)                                               \
    QRED(e3_, a03, a13, a23, a33)                                               \
    if (isL0) {                                                                 \
        const float iv = rcp1p(__fmaf_rn(xv, wxm0, bgm0) + e0_);                \
        const float fv = rcp1p(__fmaf_rn(xv, wxm1, bgm1) + e1_);                \
        const float gv = __fmaf_rn(2.f, rcp1p(__fmaf_rn(xv, wxm2, bgm2) + e2_), -1.f); \
        const float ov = rcp1p(__fmaf_rn(xv, wxm3, bgm3) + e3_);                \
        cc = __fmaf_rn(fv, cc, iv * gv);                                        \
        const float th = __fmaf_rn(2.f, rcp1p(cc * SGC), -1.f);                 \
        *(_Float16*)(wraddr + (L0WOFF)) = (_Float16)(ov * th);                  \
    } else {                                                                    \
        /* cross-half (ck vs ck+4) combine: row_ror:12 -> in[(i+4)&15].         \
           Lanes ck>=4 receive junk but never consume (ck<4 gate). */           \
        e0_ += dpp_get<0x12C>(e0_);                                             \
        e1_ += dpp_get<0x12C>(e1_);                                             \
        e2_ += dpp_get<0x12C>(e2_);                                             \
        e3_ += dpp_get<0x12C>(e3_);                                             \
        if ((DO_L1) && ck < 4) {                                                \
            const float iv = rcp1p(e0_ + bgm0);                                 \
            const float fv = rcp1p(e1_ + bgm1);                                 \
            const float gv = __fmaf_rn(2.f, rcp1p(e2_ + bgm2), -1.f);           \
            const float ov = rcp1p(e3_ + bgm3);                                 \
            cc = __fmaf_rn(fv, cc, iv * gv);                                    \
            hlast = ov * __fmaf_rn(2.f, rcp1p(cc * SGC), -1.f);                 \
            *(_Float16*)(wraddr + (L1WOFF)) = (_Float16)hlast;                  \
        }                                                                       \
    }                                                                           \
    BARRIER();                                                                  \
}

// Block = 768 threads, 4 batch rows per block, 1 block/CU.
//   waves 0-3  (tid 0..255):   layer0.  j=tid>>2, ck=tid&3  (16-wide K chunk of 64)
//   waves 4-11 (tid 256..767): layer1.  p=tid-256, j=p>>3, ck=p&7 (chunk of K=128=[h1|h2])
// Pipeline: iter i does layer0 step i and layer1 step i-1; ONE barrier per iter.
// h crosses steps through LDS as FP16 (c never quantized); dots use
// v_dot2_f32_f16 -> both the LDS-pipe load (8 ds_read_b128/lane) and the
// dot issue count (128/lane) are HALF the f32 version's.
__global__ __launch_bounds__(768, 3)
void lstm2_kernel(const float* __restrict__ x,
                  const float* __restrict__ Wih0,
                  const float* __restrict__ Whh0,
                  const float* __restrict__ bih0,
                  const float* __restrict__ bhh0,
                  const float* __restrict__ Wih1,
                  const float* __restrict__ Whh1,
                  const float* __restrict__ bih1,
                  const float* __restrict__ bhh1,
                  const float* __restrict__ fcW,
                  const float* __restrict__ fcb,
                  float* __restrict__ out)
{
    __shared__ __align__(16) float arena_f[912];
    char* const arena = (char*)arena_f;

    const int tid  = threadIdx.x;
    const int row0 = blockIdx.x * 4;

    const bool isL0 = (tid < 256);
    const int  p    = isL0 ? tid : (tid - 256);
    const int  j    = isL0 ? (p >> 2) : (p >> 3);
    const int  ck   = isL0 ? (p & 3)  : (p & 7);
    const int  ckk  = (ck < 4) ? ck : (ck - 4);
    const int  rk   = ck & 3;                      // this lane's output row
    const bool q1   = (rk & 1) != 0;
    const bool q2   = (rk & 2) != 0;

    // ---- weights: 32 packed v2h registers (fp16), gate-prescaled at pack ----
    const float* Wsrc;
    if (isL0)        Wsrc = Whh0;
    else if (ck < 4) Wsrc = Wih1;
    else             Wsrc = Whh1;
    const int kbase = 16 * ckk;
    const float* Wg0 = Wsrc + (0 * HD + j) * HD + kbase;
    const float* Wg1 = Wsrc + (1 * HD + j) * HD + kbase;
    const float* Wg2 = Wsrc + (2 * HD + j) * HD + kbase;
    const float* Wg3 = Wsrc + (3 * HD + j) * HD + kbase;
    const v2h wA0 = packw(Wg0[0],  Wg0[1],  SIC), wA1 = packw(Wg0[2],  Wg0[3],  SIC),
              wA2 = packw(Wg0[4],  Wg0[5],  SIC), wA3 = packw(Wg0[6],  Wg0[7],  SIC),
              wA4 = packw(Wg0[8],  Wg0[9],  SIC), wA5 = packw(Wg0[10], Wg0[11], SIC),
              wA6 = packw(Wg0[12], Wg0[13], SIC), wA7 = packw(Wg0[14], Wg0[15], SIC);
    const v2h wB0 = packw(Wg1[0],  Wg1[1],  SIC), wB1 = packw(Wg1[2],  Wg1[3],  SIC),
              wB2 = packw(Wg1[4],  Wg1[5],  SIC), wB3 = packw(Wg1[6],  Wg1[7],  SIC),
              wB4 = packw(Wg1[8],  Wg1[9],  SIC), wB5 = packw(Wg1[10], Wg1[11], SIC),
              wB6 = packw(Wg1[12], Wg1[13], SIC), wB7 = packw(Wg1[14], Wg1[15], SIC);
    const v2h wC0 = packw(Wg2[0],  Wg2[1],  SGC), wC1 = packw(Wg2[2],  Wg2[3],  SGC),
              wC2 = packw(Wg2[4],  Wg2[5],  SGC), wC3 = packw(Wg2[6],  Wg2[7],  SGC),
              wC4 = packw(Wg2[8],  Wg2[9],  SGC), wC5 = packw(Wg2[10], Wg2[11], SGC),
              wC6 = packw(Wg2[12], Wg2[13], SGC), wC7 = packw(Wg2[14], Wg2[15], SGC);
    const v2h wD0 = packw(Wg3[0],  Wg3[1],  SIC), wD1 = packw(Wg3[2],  Wg3[3],  SIC),
              wD2 = packw(Wg3[4],  Wg3[5],  SIC), wD3 = packw(Wg3[6],  Wg3[7],  SIC),
              wD4 = packw(Wg3[8],  Wg3[9],  SIC), wD5 = packw(Wg3[10], Wg3[11], SIC),
              wD6 = packw(Wg3[12], Wg3[13], SIC), wD7 = packw(Wg3[14], Wg3[15], SIC);

    // Biases / x-weights, f32, pre-scaled, UNMASKED (added once, post-QRED).
    float bgm0, bgm1, bgm2, bgm3, wxm0 = 0.f, wxm1 = 0.f, wxm2 = 0.f, wxm3 = 0.f;
    if (isL0) {
        bgm0 = (bih0[0*HD+j] + bhh0[0*HD+j]) * SIC;
        bgm1 = (bih0[1*HD+j] + bhh0[1*HD+j]) * SIC;
        bgm2 = (bih0[2*HD+j] + bhh0[2*HD+j]) * SGC;
        bgm3 = (bih0[3*HD+j] + bhh0[3*HD+j]) * SIC;
        wxm0 = Wih0[0*HD+j] * SIC;
        wxm1 = Wih0[1*HD+j] * SIC;
        wxm2 = Wih0[2*HD+j] * SGC;
        wxm3 = Wih0[3*HD+j] * SIC;
    } else {
        bgm0 = (bih1[0*HD+j] + bhh1[0*HD+j]) * SIC;
        bgm1 = (bih1[1*HD+j] + bhh1[1*HD+j]) * SIC;
        bgm2 = (bih1[2*HD+j] + bhh1[2*HD+j]) * SGC;
        bgm3 = (bih1[3*HD+j] + bhh1[3*HD+j]) * SIC;
    }

    // LDS read pointers: parity baked into TWO sets; each row read is 2
    // ds_read_b128 at reg+imm (row offsets 0/160/320/480).
    const int rdBase = (ck < 4) ? H1_BASE : H2_BASE;   // isL0 has ck<4
    const int rdPh   = (ck < 4) ? 1 : 0;               // h1 readers: (i+1)&1; h2: i&1
    const int coff   = ckk * 32;

    const char* pe0 = arena + rdBase + rdPh * PSTR + coff;
    const char* pe1 = pe0 + 16;
    const char* po0 = arena + rdBase + (rdPh ^ 1) * PSTR + coff;
    const char* po1 = po0 + 16;

    // writers: lane's row rk, unit j, fp16 element
    char* const wraddr = arena + (isL0 ? H1_BASE : H2_BASE) + rk * RSTR + (j << 1);

    // zero h1+h2 (both parities; [0, 2624) covers all h storage)
    for (int z = tid; z < 656; z += 768)
        *(float*)(arena + 4 * z) = 0.f;

    // Each L0 lane streams only ITS row's x (lane rk -> batch row row0+rk).
    const float* xps = x + (row0 + rk) * TT;
    float xa = 0.f, xb = 0.f;
    if (isL0) { xa = xps[0]; xb = xps[1]; }

    const float fcwj = fcW[j];
    float cc = 0.f, hlast = 0.f;

    __syncthreads();

    STEP(pe, xa, 0, PSTR, false, 2)      // i = 0: L0 only
    STEP(po, xb, PSTR, 0, true, 3)       // i = 1: first L1 step (step 0)
#pragma unroll 1
    for (int i = 2; i < TT; i += 2) {
        STEP(pe, xa, 0, PSTR, true, i + 2)
        STEP(po, xb, PSTR, 0, true, i + 3)
    }
    // tail i = 2048: layer1 step 2047 only (no L0, no h2 store needed)
    if (!isL0) {
        float a00, a01, a02, a03, a10, a11, a12, a13;
        float a20, a21, a22, a23, a30, a31, a32, a33;
        ROWDOTH(pe, 0 * RSTR, a00, a01, a02, a03)
        ROWDOTH(pe, 1 * RSTR, a10, a11, a12, a13)
        ROWDOTH(pe, 2 * RSTR, a20, a21, a22, a23)
        ROWDOTH(pe, 3 * RSTR, a30, a31, a32, a33)
        QRED(e0_, a00, a10, a20, a30)
        QRED(e1_, a01, a11, a21, a31)
        QRED(e2_, a02, a12, a22, a32)
        QRED(e3_, a03, a13, a23, a33)
        e0_ += dpp_get<0x12C>(e0_);
        e1_ += dpp_get<0x12C>(e1_);
        e2_ += dpp_get<0x12C>(e2_);
        e3_ += dpp_get<0x12C>(e3_);
        if (ck < 4) {
            const float iv = rcp1p(e0_ + bgm0);
            const float fv = rcp1p(e1_ + bgm1);
            const float gv = __fmaf_rn(2.f, rcp1p(e2_ + bgm2), -1.f);
            const float ov = rcp1p(e3_ + bgm3);
            cc = __fmaf_rn(fv, cc, iv * gv);
            hlast = ov * __fmaf_rn(2.f, rcp1p(cc * SGC), -1.f);
        }
    }
    __syncthreads();

    // ---- FC: out[row] = sum_j h2[T-1][row][j] * fcW[j] + fcb (f32 path) ----
    if (!isL0 && ck < 4)
        *(float*)(arena + FCS_BASE + ((rk * HD + j) << 2)) = hlast * fcwj;
    __syncthreads();

    if (tid < 64) {
        const int r = tid >> 4, seg = tid & 15;
        const float4 v = ((const float4*)(arena + FCS_BASE))[r * 16 + seg];
        float s = (v.x + v.y) + (v.z + v.w);
        s += __shfl_xor(s, 1, 64);
        s += __shfl_xor(s, 2, 64);
        s += __shfl_xor(s, 4, 64);
        s += __shfl_xor(s, 8, 64);
        if (seg == 0) out[row0 + r] = s + fcb[0];
    }
}

extern "C" void kernel_launch(void* const* d_in, const int* in_sizes, int n_in,
                              void* d_out, int out_size, void* d_ws, size_t ws_size,
                              hipStream_t stream) {
    const float* x    = (const float*)d_in[0];
    const float* Wih0 = (const float*)d_in[1];
    const float* Whh0 = (const float*)d_in[2];
    const float* bih0 = (const float*)d_in[3];
    const float* bhh0 = (const float*)d_in[4];
    const float* Wih1 = (const float*)d_in[5];
    const float* Whh1 = (const float*)d_in[6];
    const float* bih1 = (const float*)d_in[7];
    const float* bhh1 = (const float*)d_in[8];
    const float* fcW  = (const float*)d_in[9];
    const float* fcb  = (const float*)d_in[10];
    float* out = (float*)d_out;

    lstm2_kernel<<<256, 768, 0, stream>>>(x, Wih0, Whh0, bih0, bhh0,
                                          Wih1, Whh1, bih1, bhh1,
                                          fcW, fcb, out);
}

// Round 9
// 2774.890 us; speedup vs baseline: 13.1469x; 1.0075x over previous
//
#include <hip/hip_runtime.h>

#define TT 2048
#define HD 64

// LDS arena, h stored as FP16 (c stays f32 in registers; only h is quantized):
//   h1 : [0, 1280)      parity p at p*640, row r at r*160, unit j at j*2
//   h2 : [1296, 2576)   same layout. H2_BASE ≡ 16 (mod 128): +4-bank skew so
//                       an L1 wave's 8 read addresses (ck0..7) cover all 32
//                       banks exactly once per ds_read_b128 (R8 had ≡64 → 16-bank
//                       skew → full 2-way conflict on every L1 read).
//   fcs: [2576, 3600)   f32 FC staging
#define H1_BASE 0
#define H2_BASE 1296
#define FCS_BASE 2576
#define PSTR 640
#define RSTR 160

// Gate pre-scales folded into (fp16) weights/biases at load time:
//   sigmoid gates (i,f,o): t = -log2(e)*z   -> sigma(z) = rcp(1+exp2(t))
//   tanh gate (g):         t = -2*log2(e)*z -> tanh(z)  = 2*rcp(1+exp2(t)) - 1
#define SIC -1.4426950408889634f
#define SGC -2.8853900817779268f

#if __has_builtin(__builtin_amdgcn_exp2f)
#define EXP2F(x) __builtin_amdgcn_exp2f(x)
#else
#define EXP2F(x) __expf(0.69314718055994531f * (x))
#endif
#if __has_builtin(__builtin_amdgcn_rcpf)
#define RCPF(x) __builtin_amdgcn_rcpf(x)
#else
#define RCPF(x) (1.0f / (x))
#endif

__device__ __forceinline__ float rcp1p(float t) { return RCPF(1.0f + EXP2F(t)); }

typedef _Float16 v2h __attribute__((ext_vector_type(2)));

// v_dot2_f32_f16: 2 fp16 products + f32 accumulate in ONE VALU instr.
#if __has_builtin(__builtin_amdgcn_fdot2)
#define FDOT2(a, b, c) __builtin_amdgcn_fdot2((a), (b), (c), false)
#else
#define FDOT2(a, b, c) __fmaf_rn((float)(a)[1], (float)(b)[1], __fmaf_rn((float)(a)[0], (float)(b)[0], (c)))
#endif

static __device__ __forceinline__ v2h bch(float f) { return __builtin_bit_cast(v2h, f); }
static __device__ __forceinline__ v2h packw(float a, float b, float s) {
    v2h r; r[0] = (_Float16)(a * s); r[1] = (_Float16)(b * s); return r;
}

// pure DPP cross-lane move (stays OFF the LDS pipe).
// Receiver lane i gets in[(i-n)&15] for row_ror:n.
// 0xB1 = quad_perm xor1, 0x4E = quad_perm xor2,
// 0x12C = row_ror:12 -> out[i] = in[(i+4)&15]  (the +4 fetch, verified R5).
template<int CTRL>
__device__ __forceinline__ float dpp_get(float v) {
    return __int_as_float(__builtin_amdgcn_update_dpp(0, __float_as_int(v), CTRL, 0xF, 0xF, true));
}

// Hot-loop barrier: order LDS ops only; let vmem/scalar prefetches ride across.
#define BARRIER() asm volatile("s_waitcnt lgkmcnt(0)\n\ts_barrier" ::: "memory")

// 16-K dot for one gate: 8 fdot2, first seeds from c=0 (inline const, no mov).
#define GDOT8I(acc, W) \
    acc = FDOT2(W##0, h0_, 0.0f); \
    acc = FDOT2(W##1, h1_, acc);  \
    acc = FDOT2(W##2, h2_, acc);  \
    acc = FDOT2(W##3, h3_, acc);  \
    acc = FDOT2(W##4, h4_, acc);  \
    acc = FDOT2(W##5, h5_, acc);  \
    acc = FDOT2(W##6, h6_, acc);  \
    acc = FDOT2(W##7, h7_, acc);

// One h-row (16 fp16 = 32B) in TWO ds_read_b128; 4 gates = 32 fdot2.
// P = pointer-set prefix (pe/po), parity baked in -> reg+imm addressing.
#define ROWDOTH(P, ROFF, A0, A1, A2, A3) { \
    const float4 f0_ = *(const float4*)(P##0 + (ROFF)); \
    const float4 f1_ = *(const float4*)(P##1 + (ROFF)); \
    const v2h h0_ = bch(f0_.x), h1_ = bch(f0_.y), h2_ = bch(f0_.z), h3_ = bch(f0_.w); \
    const v2h h4_ = bch(f1_.x), h5_ = bch(f1_.y), h6_ = bch(f1_.z), h7_ = bch(f1_.w); \
    GDOT8I(A0, wA) \
    GDOT8I(A1, wB) \
    GDOT8I(A2, wC) \
    GDOT8I(A3, wD) }

// Packed row-select quad reduction: lane q (q = rk) ends with the full quad
// sum of row q's partials. 6 cndmask + 3 dpp-adds.
#define QRED(e, r0, r1, r2, r3) \
    float e; { \
        float x_ = q1 ? (r1) : (r0); float y_ = q1 ? (r0) : (r1); \
        x_ += dpp_get<0xB1>(y_); \
        float z_ = q1 ? (r3) : (r2); float w_ = q1 ? (r2) : (r3); \
        z_ += dpp_get<0xB1>(w_); \
        float u_ = q2 ? z_ : x_; float v_ = q2 ? x_ : z_; \
        e = u_ + dpp_get<0x4E>(v_); \
    }

// One pipelined timestep. P = pointer set (pe even / po odd), X = x register
// (xa even / xb odd; each L0 lane streams only ITS row rk's x stream),
// L0WOFF/L1WOFF = parity write byte offsets (0 / PSTR), DO_L1 gates L1,
// XNI = x prefetch index. Bias + x*Wih inject POST-QRED (once per lane).
#define STEP(P, X, L0WOFF, L1WOFF, DO_L1, XNI)                                  \
{                                                                               \
    float xv = 0.f;                                                             \
    if (isL0) {                                                                 \
        xv = X;                                                                 \
        const int xi_ = (XNI) < TT ? (XNI) : (TT - 1);                          \
        X = xps[xi_];                                                           \
    }                                                                           \
    float a00, a01, a02, a03, a10, a11, a12, a13;                               \
    float a20, a21, a22, a23, a30, a31, a32, a33;                               \
    ROWDOTH(P, 0 * RSTR, a00, a01, a02, a03)                                    \
    ROWDOTH(P, 1 * RSTR, a10, a11, a12, a13)                                    \
    ROWDOTH(P, 2 * RSTR, a20, a21, a22, a23)                                    \
    ROWDOTH(P, 3 * RSTR, a30, a31, a32, a33)                                    \
    QRED(e0_, a00, a10, a20, a30)                                               \
    QRED(e1_, a01, a11, a21, a31)                                               \
    QRED(e2_, a02, a12, a22, a32)                                               \
    QRED(e3_, a03, a13, a23, a33)                                               \
    if (isL0) {                                                                 \
        const float iv = rcp1p(__fmaf_rn(xv, wxm0, bgm0) + e0_);                \
        const float fv = rcp1p(__fmaf_rn(xv, wxm1, bgm1) + e1_);                \
        const float gv = __fmaf_rn(2.f, rcp1p(__fmaf_rn(xv, wxm2, bgm2) + e2_), -1.f); \
        const float ov = rcp1p(__fmaf_rn(xv, wxm3, bgm3) + e3_);                \
        cc = __fmaf_rn(fv, cc, iv * gv);                                        \
        const float th = __fmaf_rn(2.f, rcp1p(cc * SGC), -1.f);                 \
        *(_Float16*)(wraddr + (L0WOFF)) = (_Float16)(ov * th);                  \
    } else {                                                                    \
        /* cross-half (ck vs ck+4) combine: row_ror:12 -> in[(i+4)&15].         \
           Lanes ck>=4 receive junk but never consume (ck<4 gate). */           \
        e0_ += dpp_get<0x12C>(e0_);                                             \
        e1_ += dpp_get<0x12C>(e1_);                                             \
        e2_ += dpp_get<0x12C>(e2_);                                             \
        e3_ += dpp_get<0x12C>(e3_);                                             \
        if ((DO_L1) && ck < 4) {                                                \
            const float iv = rcp1p(e0_ + bgm0);                                 \
            const float fv = rcp1p(e1_ + bgm1);                                 \
            const float gv = __fmaf_rn(2.f, rcp1p(e2_ + bgm2), -1.f);           \
            const float ov = rcp1p(e3_ + bgm3);                                 \
            cc = __fmaf_rn(fv, cc, iv * gv);                                    \
            hlast = ov * __fmaf_rn(2.f, rcp1p(cc * SGC), -1.f);                 \
            *(_Float16*)(wraddr + (L1WOFF)) = (_Float16)hlast;                  \
        }                                                                       \
    }                                                                           \
    BARRIER();                                                                  \
}

// Block = 768 threads, 4 batch rows per block, 1 block/CU.
//   waves 0-3  (tid 0..255):   layer0.  j=tid>>2, ck=tid&3  (16-wide K chunk of 64)
//   waves 4-11 (tid 256..767): layer1.  p=tid-256, j=p>>3, ck=p&7 (chunk of K=128=[h1|h2])
// Pipeline: iter i does layer0 step i and layer1 step i-1; ONE barrier per iter.
// h crosses steps through LDS as FP16 (c never quantized); dots use
// v_dot2_f32_f16 -> LDS load (8 ds_read_b128/lane) and dot issue (128/lane)
// are HALF the f32 version's. H2_BASE bank-skewed so L1 reads are conflict-free.
__global__ __launch_bounds__(768, 3)
void lstm2_kernel(const float* __restrict__ x,
                  const float* __restrict__ Wih0,
                  const float* __restrict__ Whh0,
                  const float* __restrict__ bih0,
                  const float* __restrict__ bhh0,
                  const float* __restrict__ Wih1,
                  const float* __restrict__ Whh1,
                  const float* __restrict__ bih1,
                  const float* __restrict__ bhh1,
                  const float* __restrict__ fcW,
                  const float* __restrict__ fcb,
                  float* __restrict__ out)
{
    __shared__ __align__(16) float arena_f[912];
    char* const arena = (char*)arena_f;

    const int tid  = threadIdx.x;
    const int row0 = blockIdx.x * 4;

    const bool isL0 = (tid < 256);
    const int  p    = isL0 ? tid : (tid - 256);
    const int  j    = isL0 ? (p >> 2) : (p >> 3);
    const int  ck   = isL0 ? (p & 3)  : (p & 7);
    const int  ckk  = (ck < 4) ? ck : (ck - 4);
    const int  rk   = ck & 3;                      // this lane's output row
    const bool q1   = (rk & 1) != 0;
    const bool q2   = (rk & 2) != 0;

    // ---- weights: 32 packed v2h registers (fp16), gate-prescaled at pack ----
    const float* Wsrc;
    if (isL0)        Wsrc = Whh0;
    else if (ck < 4) Wsrc = Wih1;
    else             Wsrc = Whh1;
    const int kbase = 16 * ckk;
    const float* Wg0 = Wsrc + (0 * HD + j) * HD + kbase;
    const float* Wg1 = Wsrc + (1 * HD + j) * HD + kbase;
    const float* Wg2 = Wsrc + (2 * HD + j) * HD + kbase;
    const float* Wg3 = Wsrc + (3 * HD + j) * HD + kbase;
    const v2h wA0 = packw(Wg0[0],  Wg0[1],  SIC), wA1 = packw(Wg0[2],  Wg0[3],  SIC),
              wA2 = packw(Wg0[4],  Wg0[5],  SIC), wA3 = packw(Wg0[6],  Wg0[7],  SIC),
              wA4 = packw(Wg0[8],  Wg0[9],  SIC), wA5 = packw(Wg0[10], Wg0[11], SIC),
              wA6 = packw(Wg0[12], Wg0[13], SIC), wA7 = packw(Wg0[14], Wg0[15], SIC);
    const v2h wB0 = packw(Wg1[0],  Wg1[1],  SIC), wB1 = packw(Wg1[2],  Wg1[3],  SIC),
              wB2 = packw(Wg1[4],  Wg1[5],  SIC), wB3 = packw(Wg1[6],  Wg1[7],  SIC),
              wB4 = packw(Wg1[8],  Wg1[9],  SIC), wB5 = packw(Wg1[10], Wg1[11], SIC),
              wB6 = packw(Wg1[12], Wg1[13], SIC), wB7 = packw(Wg1[14], Wg1[15], SIC);
    const v2h wC0 = packw(Wg2[0],  Wg2[1],  SGC), wC1 = packw(Wg2[2],  Wg2[3],  SGC),
              wC2 = packw(Wg2[4],  Wg2[5],  SGC), wC3 = packw(Wg2[6],  Wg2[7],  SGC),
              wC4 = packw(Wg2[8],  Wg2[9],  SGC), wC5 = packw(Wg2[10], Wg2[11], SGC),
              wC6 = packw(Wg2[12], Wg2[13], SGC), wC7 = packw(Wg2[14], Wg2[15], SGC);
    const v2h wD0 = packw(Wg3[0],  Wg3[1],  SIC), wD1 = packw(Wg3[2],  Wg3[3],  SIC),
              wD2 = packw(Wg3[4],  Wg3[5],  SIC), wD3 = packw(Wg3[6],  Wg3[7],  SIC),
              wD4 = packw(Wg3[8],  Wg3[9],  SIC), wD5 = packw(Wg3[10], Wg3[11], SIC),
              wD6 = packw(Wg3[12], Wg3[13], SIC), wD7 = packw(Wg3[14], Wg3[15], SIC);

    // Biases / x-weights, f32, pre-scaled, UNMASKED (added once, post-QRED).
    float bgm0, bgm1, bgm2, bgm3, wxm0 = 0.f, wxm1 = 0.f, wxm2 = 0.f, wxm3 = 0.f;
    if (isL0) {
        bgm0 = (bih0[0*HD+j] + bhh0[0*HD+j]) * SIC;
        bgm1 = (bih0[1*HD+j] + bhh0[1*HD+j]) * SIC;
        bgm2 = (bih0[2*HD+j] + bhh0[2*HD+j]) * SGC;
        bgm3 = (bih0[3*HD+j] + bhh0[3*HD+j]) * SIC;
        wxm0 = Wih0[0*HD+j] * SIC;
        wxm1 = Wih0[1*HD+j] * SIC;
        wxm2 = Wih0[2*HD+j] * SGC;
        wxm3 = Wih0[3*HD+j] * SIC;
    } else {
        bgm0 = (bih1[0*HD+j] + bhh1[0*HD+j]) * SIC;
        bgm1 = (bih1[1*HD+j] + bhh1[1*HD+j]) * SIC;
        bgm2 = (bih1[2*HD+j] + bhh1[2*HD+j]) * SGC;
        bgm3 = (bih1[3*HD+j] + bhh1[3*HD+j]) * SIC;
    }

    // LDS read pointers: parity baked into TWO sets; each row read is 2
    // ds_read_b128 at reg+imm (row offsets 0/160/320/480).
    const int rdBase = (ck < 4) ? H1_BASE : H2_BASE;   // isL0 has ck<4
    const int rdPh   = (ck < 4) ? 1 : 0;               // h1 readers: (i+1)&1; h2: i&1
    const int coff   = ckk * 32;

    const char* pe0 = arena + rdBase + rdPh * PSTR + coff;
    const char* pe1 = pe0 + 16;
    const char* po0 = arena + rdBase + (rdPh ^ 1) * PSTR + coff;
    const char* po1 = po0 + 16;

    // writers: lane's row rk, unit j, fp16 element
    char* const wraddr = arena + (isL0 ? H1_BASE : H2_BASE) + rk * RSTR + (j << 1);

    // zero h1+h2 (both parities; [0, 2576) covers all h storage)
    for (int z = tid; z < 644; z += 768)
        *(float*)(arena + 4 * z) = 0.f;

    // Each L0 lane streams only ITS row's x (lane rk -> batch row row0+rk).
    const float* xps = x + (row0 + rk) * TT;
    float xa = 0.f, xb = 0.f;
    if (isL0) { xa = xps[0]; xb = xps[1]; }

    const float fcwj = fcW[j];
    float cc = 0.f, hlast = 0.f;

    __syncthreads();

    STEP(pe, xa, 0, PSTR, false, 2)      // i = 0: L0 only
    STEP(po, xb, PSTR, 0, true, 3)       // i = 1: first L1 step (step 0)
#pragma unroll 1
    for (int i = 2; i < TT; i += 2) {
        STEP(pe, xa, 0, PSTR, true, i + 2)
        STEP(po, xb, PSTR, 0, true, i + 3)
    }
    // tail i = 2048: layer1 step 2047 only (no L0, no h2 store needed)
    if (!isL0) {
        float a00, a01, a02, a03, a10, a11, a12, a13;
        float a20, a21, a22, a23, a30, a31, a32, a33;
        ROWDOTH(pe, 0 * RSTR, a00, a01, a02, a03)
        ROWDOTH(pe, 1 * RSTR, a10, a11, a12, a13)
        ROWDOTH(pe, 2 * RSTR, a20, a21, a22, a23)
        ROWDOTH(pe, 3 * RSTR, a30, a31, a32, a33)
        QRED(e0_, a00, a10, a20, a30)
        QRED(e1_, a01, a11, a21, a31)
        QRED(e2_, a02, a12, a22, a32)
        QRED(e3_, a03, a13, a23, a33)
        e0_ += dpp_get<0x12C>(e0_);
        e1_ += dpp_get<0x12C>(e1_);
        e2_ += dpp_get<0x12C>(e2_);
        e3_ += dpp_get<0x12C>(e3_);
        if (ck < 4) {
            const float iv = rcp1p(e0_ + bgm0);
            const float fv = rcp1p(e1_ + bgm1);
            const float gv = __fmaf_rn(2.f, rcp1p(e2_ + bgm2), -1.f);
            const float ov = rcp1p(e3_ + bgm3);
            cc = __fmaf_rn(fv, cc, iv * gv);
            hlast = ov * __fmaf_rn(2.f, rcp1p(cc * SGC), -1.f);
        }
    }
    __syncthreads();

    // ---- FC: out[row] = sum_j h2[T-1][row][j] * fcW[j] + fcb (f32 path) ----
    if (!isL0 && ck < 4)
        *(float*)(arena + FCS_BASE + ((rk * HD + j) << 2)) = hlast * fcwj;
    __syncthreads();

    if (tid < 64) {
        const int r = tid >> 4, seg = tid & 15;
        const float4 v = ((const float4*)(arena + FCS_BASE))[r * 16 + seg];
        float s = (v.x + v.y) + (v.z + v.w);
        s += __shfl_xor(s, 1, 64);
        s += __shfl_xor(s, 2, 64);
        s += __shfl_xor(s, 4, 64);
        s += __shfl_xor(s, 8, 64);
        if (seg == 0) out[row0 + r] = s + fcb[0];
    }
}

extern "C" void kernel_launch(void* const* d_in, const int* in_sizes, int n_in,
                              void* d_out, int out_size, void* d_ws, size_t ws_size,
                              hipStream_t stream) {
    const float* x    = (const float*)d_in[0];
    const float* Wih0 = (const float*)d_in[1];
    const float* Whh0 = (const float*)d_in[2];
    const float* bih0 = (const float*)d_in[3];
    const float* bhh0 = (const float*)d_in[4];
    const float* Wih1 = (const float*)d_in[5];
    const float* Whh1 = (const float*)d_in[6];
    const float* bih1 = (const float*)d_in[7];
    const float* bhh1 = (const float*)d_in[8];
    const float* fcW  = (const float*)d_in[9];
    const float* fcb  = (const float*)d_in[10];
    float* out = (float*)d_out;

    lstm2_kernel<<<256, 768, 0, stream>>>(x, Wih0, Whh0, bih0, bhh0,
                                          Wih1, Whh1, bih1, bhh1,
                                          fcW, fcb, out);
}